// Round 1
// baseline (6031.747 us; speedup 1.0000x reference)
//
#include <hip/hip_runtime.h>
#include <math.h>

// Problem constants (from reference setup_inputs)
#define B      2
#define C      128     // channels
#define H      256     // d_model == image height
#define W      512     // image width
#define NCOND  512
#define DCOND  512
#define DATTN  256
#define KKEEP  204     // int(256 * (1 - 0.2))

// Workspace layout (float offsets). Total = 34,374,656 floats = ~131.2 MB.
#define OFF_K     0           // k proj    [B][NCOND][DATTN] = 262144
#define OFF_V     262144      // val proj  262144
#define OFF_BIN   524288      // binary[256]
#define OFF_STATS 524544      // 64 groups * 4 quarters * 2 = 512
#define OFF_WT    525312      // transposed conv weights [2C*9][C] = 294912
#define OFF_AF    820224      // attn_feature [B][C][H][W] = 33554432

// ---------------------------------------------------------------------------
// Learned mask: binary[h] = 1 iff sigmoid(mask_w[h]) is among the top-204.
// (binary = probs + sg(hard - probs) == hard == (wta > 0) == comp.)
__global__ void k_binary(const float* __restrict__ mask_w, float* __restrict__ bin) {
    __shared__ float s[H];
    int t = threadIdx.x;
    float sv = 1.0f / (1.0f + __expf(-mask_w[t]));
    s[t] = sv;
    __syncthreads();
    int cnt = 0;
    for (int j = 0; j < H; ++j) cnt += (s[j] > sv) ? 1 : 0;
    bin[t] = (cnt < KKEEP) ? 1.0f : 0.0f;
}

// binary_mask output: [B][1][W][H], value depends only on h.
__global__ void k_maskout(const float* __restrict__ bin, float* __restrict__ mout) {
    int i = blockIdx.x * 256 + threadIdx.x;
    if (i < B * W * H) mout[i] = bin[i & (H - 1)];
}

// ---------------------------------------------------------------------------
// K/V projection: one block per (b, n) row of v.
__global__ void k_kv(const float* __restrict__ v, const float* __restrict__ Wk,
                     const float* __restrict__ Wv, float* __restrict__ kbuf,
                     float* __restrict__ vbuf) {
    __shared__ float vrow[DCOND];
    int bn = blockIdx.x;              // b*NCOND + n
    int t  = threadIdx.x;             // output column e
    const float* vp = v + bn * DCOND;
    for (int i = t; i < DCOND; i += 256) vrow[i] = vp[i];
    __syncthreads();
    float ka = 0.f, va = 0.f;
    for (int d4 = 0; d4 < DCOND / 4; ++d4) {
        float4 vv = *(const float4*)(vrow + d4 * 4);
        const float* wk = Wk + (d4 * 4) * DATTN + t;
        const float* wv = Wv + (d4 * 4) * DATTN + t;
        ka += vv.x * wk[0];         va += vv.x * wv[0];
        ka += vv.y * wk[DATTN];     va += vv.y * wv[DATTN];
        ka += vv.z * wk[2 * DATTN]; va += vv.z * wv[2 * DATTN];
        ka += vv.w * wk[3 * DATTN]; va += vv.w * wv[3 * DATTN];
    }
    kbuf[bn * DATTN + t] = ka;
    vbuf[bn * DATTN + t] = va;
}

// ---------------------------------------------------------------------------
// Transpose conv weights [co][ci][ky][kx] -> [ci*9+ky*3+kx][co] for coalesced reads.
__global__ void k_wt(const float* __restrict__ cw, float* __restrict__ wt) {
    int i = blockIdx.x * 256 + threadIdx.x;
    if (i >= C * 2 * C * 9) return;
    int co = i & 127;
    int r  = i >> 7;            // ci*9 + ky*3 + kx
    int kx = r % 3; int r2 = r / 3;
    int ky = r2 % 3; int ci = r2 / 3;
    wt[i] = cw[((co * (2 * C) + ci) * 3 + ky) * 3 + kx];
}

// ---------------------------------------------------------------------------
// Fused cross-attention: block handles 16 rows (b, ci, wi0..wi0+15).
// Phases: load X -> Q -> scores -> softmax -> PV -> output projection.
// LDS: rgA = Xs[256][16] then St[512][16] (aliased); rgB = Qs/Os [16][260].
__launch_bounds__(256)
__global__ void k_attn(const float* __restrict__ x, const float* __restrict__ Wq,
                       const float* __restrict__ kbuf, const float* __restrict__ vbuf,
                       const float* __restrict__ Wo, const float* __restrict__ bo,
                       float* __restrict__ af) {
    __shared__ float rgA[512 * 16];     // 32 KB
    __shared__ float rgB[16 * 260];     // 16.6 KB
    const int t   = threadIdx.x;
    const int blk = blockIdx.x;
    const int b   = blk >> 12;          // 4096 blocks per batch
    const int rem = blk & 4095;
    const int ci  = rem >> 5;
    const int wi0 = (rem & 31) << 4;

    // ---- load X tile: Xs[h][r] = x[b, ci, h, wi0+r]
    const float* xbase = x + ((b * C + ci) * H) * W + wi0;
    for (int i = t; i < H * 16; i += 256) {
        int h = i >> 4, r = i & 15;
        rgA[i] = xbase[h * W + r];
    }
    __syncthreads();

    // ---- Q: thread t owns output column d=t; acc[r] = q[r][t]
    {
        float acc[16];
#pragma unroll
        for (int r = 0; r < 16; ++r) acc[r] = 0.f;
        const float* wq = Wq + t;
        for (int h = 0; h < H; ++h) {
            float w = wq[h * DATTN];
            const float4* xr = (const float4*)(rgA + h * 16);
            float4 x0 = xr[0], x1 = xr[1], x2 = xr[2], x3 = xr[3];
            acc[0]  += x0.x * w; acc[1]  += x0.y * w; acc[2]  += x0.z * w; acc[3]  += x0.w * w;
            acc[4]  += x1.x * w; acc[5]  += x1.y * w; acc[6]  += x1.z * w; acc[7]  += x1.w * w;
            acc[8]  += x2.x * w; acc[9]  += x2.y * w; acc[10] += x2.z * w; acc[11] += x2.w * w;
            acc[12] += x3.x * w; acc[13] += x3.y * w; acc[14] += x3.z * w; acc[15] += x3.w * w;
        }
#pragma unroll
        for (int r = 0; r < 16; ++r) rgB[r * 260 + t] = acc[r];
    }
    __syncthreads();

    // ---- scores: St[n][r] = sum_d Qs[r][d] * k[b][n][d]  (no softmax scale in ref)
    {
        const int r = t & 15, g = t >> 4;
        const float4* qrow = (const float4*)(rgB + r * 260);
        const float* kb = kbuf + b * NCOND * DATTN;
        for (int kk = 0; kk < 32; ++kk) {
            int n = g + (kk << 4);
            const float4* kr = (const float4*)(kb + n * DATTN);
            float sx = 0.f, sy = 0.f, sz = 0.f, sw = 0.f;
#pragma unroll 8
            for (int d4 = 0; d4 < 64; ++d4) {
                float4 q4 = qrow[d4]; float4 k4 = kr[d4];
                sx += q4.x * k4.x; sy += q4.y * k4.y;
                sz += q4.z * k4.z; sw += q4.w * k4.w;
            }
            rgA[n * 16 + r] = (sx + sy) + (sz + sw);
        }
    }
    __syncthreads();

    // ---- softmax over n (512) per row r: 16 lanes per row, strided n
    {
        const int r = t >> 4, j = t & 15;
        float m = -1e30f;
        for (int kk = 0; kk < 32; ++kk) m = fmaxf(m, rgA[(j + (kk << 4)) * 16 + r]);
#pragma unroll
        for (int o = 8; o >= 1; o >>= 1) m = fmaxf(m, __shfl_xor(m, o, 16));
        float s = 0.f;
        for (int kk = 0; kk < 32; ++kk) {
            int idx = (j + (kk << 4)) * 16 + r;
            float e = __expf(rgA[idx] - m);
            rgA[idx] = e; s += e;
        }
#pragma unroll
        for (int o = 8; o >= 1; o >>= 1) s += __shfl_xor(s, o, 16);
        float rinv = 1.0f / s;
        for (int kk = 0; kk < 32; ++kk) rgA[(j + (kk << 4)) * 16 + r] *= rinv;
    }
    __syncthreads();

    // ---- PV: thread (d4 = t&63, rq = t>>6) computes out[rq*4..+3][d4*4..+3]
    {
        const int d4 = t & 63, rq = t >> 6;
        float acc[16];
#pragma unroll
        for (int i = 0; i < 16; ++i) acc[i] = 0.f;
        const float4* vb = (const float4*)(vbuf + b * NCOND * DATTN) + d4;
        for (int n = 0; n < NCOND; ++n) {
            float4 v4 = vb[n * 64];
            float4 p4 = *(const float4*)(rgA + n * 16 + rq * 4);
            acc[0]  += p4.x * v4.x; acc[1]  += p4.x * v4.y; acc[2]  += p4.x * v4.z; acc[3]  += p4.x * v4.w;
            acc[4]  += p4.y * v4.x; acc[5]  += p4.y * v4.y; acc[6]  += p4.y * v4.z; acc[7]  += p4.y * v4.w;
            acc[8]  += p4.z * v4.x; acc[9]  += p4.z * v4.y; acc[10] += p4.z * v4.z; acc[11] += p4.z * v4.w;
            acc[12] += p4.w * v4.x; acc[13] += p4.w * v4.y; acc[14] += p4.w * v4.z; acc[15] += p4.w * v4.w;
        }
#pragma unroll
        for (int rl = 0; rl < 4; ++rl) {
            float4 o4 = make_float4(acc[rl * 4 + 0], acc[rl * 4 + 1], acc[rl * 4 + 2], acc[rl * 4 + 3]);
            *(float4*)(rgB + (rq * 4 + rl) * 260 + d4 * 4) = o4;
        }
    }
    __syncthreads();

    // ---- output projection: thread (r = t&15, hg = t>>4) -> feat[r][hg*16..+15]
    {
        const int r = t & 15, hg = t >> 4;
        float acc[16];
#pragma unroll
        for (int i = 0; i < 16; ++i) acc[i] = 0.f;
        const float4* orow = (const float4*)(rgB + r * 260);
        const float* wob = Wo + hg * 16;
        for (int d4 = 0; d4 < 64; ++d4) {
            float4 o4 = orow[d4];
#define PROJ_STEP(OD, DL)                                                      \
            {                                                                  \
                const float4* wr = (const float4*)(wob + (d4 * 4 + DL) * DATTN); \
                float4 wa = wr[0], wb2 = wr[1], wc = wr[2], wd = wr[3];        \
                acc[0]  += (OD) * wa.x;  acc[1]  += (OD) * wa.y;               \
                acc[2]  += (OD) * wa.z;  acc[3]  += (OD) * wa.w;               \
                acc[4]  += (OD) * wb2.x; acc[5]  += (OD) * wb2.y;              \
                acc[6]  += (OD) * wb2.z; acc[7]  += (OD) * wb2.w;              \
                acc[8]  += (OD) * wc.x;  acc[9]  += (OD) * wc.y;               \
                acc[10] += (OD) * wc.z;  acc[11] += (OD) * wc.w;               \
                acc[12] += (OD) * wd.x;  acc[13] += (OD) * wd.y;               \
                acc[14] += (OD) * wd.z;  acc[15] += (OD) * wd.w;               \
            }
            PROJ_STEP(o4.x, 0)
            PROJ_STEP(o4.y, 1)
            PROJ_STEP(o4.z, 2)
            PROJ_STEP(o4.w, 3)
#undef PROJ_STEP
        }
        const float4* bp = (const float4*)(bo + hg * 16);
        float4 b0 = bp[0], b1 = bp[1], b2 = bp[2], b3 = bp[3];
        float* ob = af + ((b * C + ci) * H + hg * 16) * W + wi0 + r;
        ob[0 * W]  = acc[0]  + b0.x; ob[1 * W]  = acc[1]  + b0.y;
        ob[2 * W]  = acc[2]  + b0.z; ob[3 * W]  = acc[3]  + b0.w;
        ob[4 * W]  = acc[4]  + b1.x; ob[5 * W]  = acc[5]  + b1.y;
        ob[6 * W]  = acc[6]  + b1.z; ob[7 * W]  = acc[7]  + b1.w;
        ob[8 * W]  = acc[8]  + b2.x; ob[9 * W]  = acc[9]  + b2.y;
        ob[10 * W] = acc[10] + b2.z; ob[11 * W] = acc[11] + b2.w;
        ob[12 * W] = acc[12] + b3.x; ob[13 * W] = acc[13] + b3.y;
        ob[14 * W] = acc[14] + b3.z; ob[15 * W] = acc[15] + b3.w;
    }
}

// ---------------------------------------------------------------------------
// conv3x3 on cat([x*binary, attn_feature]) + bias -> raw hh into d_out.
// Block: (b, y, x-tile of 64) x all 128 co. thread: co = t&127, xg = t>>7 (32 x each).
#define CKC 32
__launch_bounds__(256)
__global__ void k_conv(const float* __restrict__ x, const float* __restrict__ af,
                       const float* __restrict__ bin, const float* __restrict__ wt,
                       const float* __restrict__ conv_b, float* __restrict__ out) {
    __shared__ float in_lds[CKC * 3 * 68];   // [cc][yy][xx] rows padded to 68 for f4 align
    const int t  = threadIdx.x;
    const int blk = blockIdx.x;
    const int xt = blk & 7;
    const int y  = (blk >> 3) & 255;
    const int b  = blk >> 11;
    const int x0 = xt * 64;
    const int co = t & 127, xg = t >> 7;

    float acc[32];
#pragma unroll
    for (int j = 0; j < 32; ++j) acc[j] = 0.f;

    for (int cb = 0; cb < 2 * C; cb += CKC) {
        __syncthreads();
        // stage input chunk: 66 valid columns (x0-1 .. x0+64), zero-padded edges
        for (int i = t; i < CKC * 204; i += 256) {
            int cc = i / 204; int rr = i - cc * 204;
            int yy = rr / 68; int xx = rr - yy * 68;
            if (xx < 66) {
                int cii = cb + cc;
                int iy = y + yy - 1;
                int ix = x0 + xx - 1;
                float vv = 0.f;
                if ((unsigned)iy < H && (unsigned)ix < W) {
                    if (cii < C) vv = x[((b * C + cii) * H + iy) * W + ix] * bin[iy];
                    else         vv = af[((b * C + (cii - C)) * H + iy) * W + ix];
                }
                in_lds[i] = vv;
            }
        }
        __syncthreads();
        for (int cc = 0; cc < CKC; ++cc) {
            const float* wrow = wt + (cb + cc) * 9 * 128 + co;
#pragma unroll
            for (int ky = 0; ky < 3; ++ky) {
                float w0 = wrow[(ky * 3 + 0) * 128];
                float w1 = wrow[(ky * 3 + 1) * 128];
                float w2 = wrow[(ky * 3 + 2) * 128];
                const float* row = in_lds + cc * 204 + ky * 68 + xg * 32;
#pragma unroll
                for (int jc = 0; jc < 4; ++jc) {
                    const float4* rp = (const float4*)(row + jc * 8);
                    float4 ra = rp[0], rb = rp[1];
                    float2 rc = *(const float2*)(row + jc * 8 + 8);
                    float r0 = ra.x, r1 = ra.y, r2 = ra.z, r3 = ra.w;
                    float r4 = rb.x, r5 = rb.y, r6 = rb.z, r7 = rb.w;
                    float r8 = rc.x, r9 = rc.y;
                    acc[jc * 8 + 0] += w0 * r0 + w1 * r1 + w2 * r2;
                    acc[jc * 8 + 1] += w0 * r1 + w1 * r2 + w2 * r3;
                    acc[jc * 8 + 2] += w0 * r2 + w1 * r3 + w2 * r4;
                    acc[jc * 8 + 3] += w0 * r3 + w1 * r4 + w2 * r5;
                    acc[jc * 8 + 4] += w0 * r4 + w1 * r5 + w2 * r6;
                    acc[jc * 8 + 5] += w0 * r5 + w1 * r6 + w2 * r7;
                    acc[jc * 8 + 6] += w0 * r6 + w1 * r7 + w2 * r8;
                    acc[jc * 8 + 7] += w0 * r7 + w1 * r8 + w2 * r9;
                }
            }
        }
    }
    float bias = conv_b[co];
    float* op = out + ((b * C + co) * H + y) * W + x0 + xg * 32;
#pragma unroll
    for (int j4 = 0; j4 < 8; ++j4) {
        float4 o = make_float4(acc[j4 * 4 + 0] + bias, acc[j4 * 4 + 1] + bias,
                               acc[j4 * 4 + 2] + bias, acc[j4 * 4 + 3] + bias);
        *(float4*)(op + j4 * 4) = o;
    }
}

// ---------------------------------------------------------------------------
// GroupNorm stats: 256 blocks = (b, g, quarter); each reduces 131072 contiguous floats.
__global__ void k_stats(const float* __restrict__ out, float* __restrict__ stats) {
    __shared__ float2 red[256];
    int blk = blockIdx.x;
    int q = blk & 3, g = (blk >> 2) & 31, b = blk >> 7;
    const float4* p = (const float4*)(out + ((b * C + g * 4) * H) * W + q * 131072);
    float s = 0.f, ss = 0.f;
    for (int i = threadIdx.x; i < 32768; i += 256) {
        float4 v = p[i];
        s  += (v.x + v.y) + (v.z + v.w);
        ss += (v.x * v.x + v.y * v.y) + (v.z * v.z + v.w * v.w);
    }
    red[threadIdx.x] = make_float2(s, ss);
    __syncthreads();
    for (int o = 128; o >= 1; o >>= 1) {
        if (threadIdx.x < o) {
            float2 a = red[threadIdx.x], c = red[threadIdx.x + o];
            red[threadIdx.x] = make_float2(a.x + c.x, a.y + c.y);
        }
        __syncthreads();
    }
    if (threadIdx.x == 0) { stats[blk * 2] = red[0].x; stats[blk * 2 + 1] = red[0].y; }
}

// GroupNorm normalize + affine + SiLU, in place on d_out.
__global__ void k_norm(const float* __restrict__ stats, const float* __restrict__ gamma,
                       const float* __restrict__ beta, float* __restrict__ out) {
    const int N4 = B * C * H * W / 4;
    int stride = gridDim.x * 256;
    for (int i4 = blockIdx.x * 256 + threadIdx.x; i4 < N4; i4 += stride) {
        int i = i4 * 4;
        int c = (i >> 17) & 127;
        int b = i >> 24;
        int g = c >> 2;
        int sb = (b * 128 + g * 4) * 2;
        float s  = stats[sb]     + stats[sb + 2] + stats[sb + 4] + stats[sb + 6];
        float ss = stats[sb + 1] + stats[sb + 3] + stats[sb + 5] + stats[sb + 7];
        const float inv = 1.0f / 524288.0f;
        float mean = s * inv;
        float var  = ss * inv - mean * mean;
        float rstd = rsqrtf(var + 1e-6f);
        float ga = gamma[c], be = beta[c];
        float4 v = *(float4*)(out + i);
        float n0 = (v.x - mean) * rstd * ga + be;
        float n1 = (v.y - mean) * rstd * ga + be;
        float n2 = (v.z - mean) * rstd * ga + be;
        float n3 = (v.w - mean) * rstd * ga + be;
        v.x = n0 / (1.0f + __expf(-n0));
        v.y = n1 / (1.0f + __expf(-n1));
        v.z = n2 / (1.0f + __expf(-n2));
        v.w = n3 / (1.0f + __expf(-n3));
        *(float4*)(out + i) = v;
    }
}

// ---------------------------------------------------------------------------
extern "C" void kernel_launch(void* const* d_in, const int* in_sizes, int n_in,
                              void* d_out, int out_size, void* d_ws, size_t ws_size,
                              hipStream_t stream) {
    const float* x      = (const float*)d_in[0];
    const float* v      = (const float*)d_in[1];
    const float* Wq     = (const float*)d_in[2];
    const float* Wk     = (const float*)d_in[3];
    const float* Wv     = (const float*)d_in[4];
    const float* Wo     = (const float*)d_in[5];
    const float* bo     = (const float*)d_in[6];
    const float* mask_w = (const float*)d_in[7];
    const float* conv_w = (const float*)d_in[8];
    const float* conv_b = (const float*)d_in[9];
    const float* gng    = (const float*)d_in[10];
    const float* gnb    = (const float*)d_in[11];

    float* out  = (float*)d_out;                 // [B][C][H][W] then mask [B][1][W][H]
    float* mout = out + B * C * H * W;
    float* ws   = (float*)d_ws;                  // needs ~131.2 MB
    float* kbuf   = ws + OFF_K;
    float* vbuf   = ws + OFF_V;
    float* bin    = ws + OFF_BIN;
    float* stats  = ws + OFF_STATS;
    float* wtbuf  = ws + OFF_WT;
    float* afbuf  = ws + OFF_AF;

    k_binary <<<1,    256, 0, stream>>>(mask_w, bin);
    k_maskout<<<1024, 256, 0, stream>>>(bin, mout);
    k_kv     <<<B * NCOND, 256, 0, stream>>>(v, Wk, Wv, kbuf, vbuf);
    k_wt     <<<1152, 256, 0, stream>>>(conv_w, wtbuf);
    k_attn   <<<8192, 256, 0, stream>>>(x, Wq, kbuf, vbuf, Wo, bo, afbuf);
    k_conv   <<<4096, 256, 0, stream>>>(x, afbuf, bin, wtbuf, conv_b, out);
    k_stats  <<<256,  256, 0, stream>>>(out, stats);
    k_norm   <<<2048, 256, 0, stream>>>(stats, gng, gnb, out);
}

// Round 2
// 3002.415 us; speedup vs baseline: 2.0090x; 2.0090x over previous
//
#include <hip/hip_runtime.h>
#include <math.h>

// Problem constants (from reference setup_inputs)
#define B      2
#define C      128     // channels
#define H      256     // d_model == image height
#define W      512     // image width
#define NCOND  512
#define DCOND  512
#define DATTN  256
#define KKEEP  204     // int(256 * (1 - 0.2))

// Workspace layout (byte offsets).
#define WS_K16    0u            // bf16 k proj [B][NCOND][DATTN]      524288 B
#define WS_VT16   524288u       // bf16 v proj transposed [B][DATTN][NCOND] 524288 B
#define WS_WQT    1048576u      // bf16 Wq^T [d][h]                   131072 B
#define WS_WOT    1179648u      // bf16 Wo^T [h][d]                   131072 B
#define WS_BIN    1310720u      // f32 binary[256]
#define WS_STATS  1311744u      // f32 stats[512]
#define WS_WT     1313792u      // f32 transposed conv weights        1179648 B
#define WS_AF     2493440u      // f32 attn_feature [B][C][H][W]      134217728 B

typedef __attribute__((ext_vector_type(8))) short bf16x8;
typedef __attribute__((ext_vector_type(4))) float f32x4;

__device__ inline ushort f2bf(float f) {
    union { float f; unsigned u; } v; v.f = f;
    unsigned r = v.u + 0x7fffu + ((v.u >> 16) & 1u);   // RNE
    return (ushort)(r >> 16);
}

// ---------------------------------------------------------------------------
// Learned mask: binary[h] = 1 iff sigmoid(mask_w[h]) is among the top-204.
__global__ void k_binary(const float* __restrict__ mask_w, float* __restrict__ bin) {
    __shared__ float s[H];
    int t = threadIdx.x;
    float sv = 1.0f / (1.0f + __expf(-mask_w[t]));
    s[t] = sv;
    __syncthreads();
    int cnt = 0;
    for (int j = 0; j < H; ++j) cnt += (s[j] > sv) ? 1 : 0;
    bin[t] = (cnt < KKEEP) ? 1.0f : 0.0f;
}

__global__ void k_maskout(const float* __restrict__ bin, float* __restrict__ mout) {
    int i = blockIdx.x * 256 + threadIdx.x;
    if (i < B * W * H) mout[i] = bin[i & (H - 1)];
}

// ---------------------------------------------------------------------------
// K/V projection -> bf16. k16: [b][n][d] row-major. vT16: [b][d][n].
__global__ void k_kv(const float* __restrict__ v, const float* __restrict__ Wk,
                     const float* __restrict__ Wv, ushort* __restrict__ k16,
                     ushort* __restrict__ vT16) {
    __shared__ float vrow[DCOND];
    int bn = blockIdx.x;              // b*NCOND + n
    int t  = threadIdx.x;             // output column e
    const float* vp = v + bn * DCOND;
    for (int i = t; i < DCOND; i += 256) vrow[i] = vp[i];
    __syncthreads();
    float ka = 0.f, va = 0.f;
    for (int d4 = 0; d4 < DCOND / 4; ++d4) {
        float4 vv = *(const float4*)(vrow + d4 * 4);
        const float* wk = Wk + (d4 * 4) * DATTN + t;
        const float* wv = Wv + (d4 * 4) * DATTN + t;
        ka += vv.x * wk[0];         va += vv.x * wv[0];
        ka += vv.y * wk[DATTN];     va += vv.y * wv[DATTN];
        ka += vv.z * wk[2 * DATTN]; va += vv.z * wv[2 * DATTN];
        ka += vv.w * wk[3 * DATTN]; va += vv.w * wv[3 * DATTN];
    }
    k16[bn * DATTN + t] = f2bf(ka);
    int b = bn >> 9, n = bn & 511;
    vT16[b * (DATTN * NCOND) + t * NCOND + n] = f2bf(va);
}

// Wq^T [d][h], Wo^T [h][d] in bf16.
__global__ void k_prep(const float* __restrict__ Wq, const float* __restrict__ Wo,
                       ushort* __restrict__ wqT, ushort* __restrict__ woT) {
    int i = blockIdx.x * 256 + threadIdx.x;
    if (i < 65536) {
        int d = i >> 8, h = i & 255;
        wqT[i] = f2bf(Wq[h * 256 + d]);
    } else {
        int j = i - 65536;
        int h = j >> 8, d = j & 255;
        woT[j] = f2bf(Wo[d * 256 + h]);
    }
}

// Transpose conv weights [co][ci][ky][kx] -> [ci*9+ky*3+kx][co].
__global__ void k_wt(const float* __restrict__ cw, float* __restrict__ wt) {
    int i = blockIdx.x * 256 + threadIdx.x;
    if (i >= C * 2 * C * 9) return;
    int co = i & 127;
    int r  = i >> 7;
    int kx = r % 3; int r2 = r / 3;
    int ky = r2 % 3; int ci = r2 / 3;
    wt[i] = cw[((co * (2 * C) + ci) * 3 + ky) * 3 + kx];
}

// ---------------------------------------------------------------------------
// Fused MFMA cross-attention. Block = 32 rows (b, ci, w0..w0+31), 4 waves.
// All GEMMs in B^T (K-major both operands) form, mfma_f32_16x16x32_bf16.
// LDS arena: [0,32768)  Xs (32x256 bf16, stride 512B) then P (32x512 bf16, stride 1024B)
//            [32768,49152) Qs then Os (32x256 bf16, stride 512B)
//            [49152,49664) smax[32][4]   [49664,50176) ssum[32][4]
// All tiles XOR-swizzled: byte_in_row ^= ((row&7)<<4).
__launch_bounds__(256)
__global__ void k_attn(const float* __restrict__ x, const ushort* __restrict__ k16,
                       const ushort* __restrict__ vT16, const ushort* __restrict__ wqT,
                       const ushort* __restrict__ woT, const float* __restrict__ bo,
                       float* __restrict__ af) {
    __shared__ __align__(16) char arena[50176];
    char* arenaB = arena + 32768;
    float* smax = (float*)(arena + 49152);
    float* ssum = (float*)(arena + 49664);

    const int t   = threadIdx.x;
    const int blk = blockIdx.x;
    const int b   = blk >> 11;
    const int ci  = (blk >> 4) & 127;
    const int w0  = (blk & 15) << 5;
    const int wid = t >> 6;
    const int lr  = t & 15;           // lane & 15
    const int lg  = (t & 63) >> 4;    // lane >> 4

    // ---- Phase 1: load X tile -> Xs[w][h] bf16 (thread t = h)
    {
        const float* xp = x + (((size_t)b * C + ci) * H + t) * W + w0;
#pragma unroll
        for (int j4 = 0; j4 < 8; ++j4) {
            float4 v4 = *(const float4*)(xp + j4 * 4);
            int j = j4 * 4;
            *(ushort*)(arena + (j + 0) * 512 + ((2 * t) ^ (((j + 0) & 7) << 4))) = f2bf(v4.x);
            *(ushort*)(arena + (j + 1) * 512 + ((2 * t) ^ (((j + 1) & 7) << 4))) = f2bf(v4.y);
            *(ushort*)(arena + (j + 2) * 512 + ((2 * t) ^ (((j + 2) & 7) << 4))) = f2bf(v4.z);
            *(ushort*)(arena + (j + 3) * 512 + ((2 * t) ^ (((j + 3) & 7) << 4))) = f2bf(v4.w);
        }
    }
    __syncthreads();

    // ---- Phase 2: Q = Xs @ WqT  -> Qs (arenaB)
    {
        f32x4 qac[2][4];
#pragma unroll
        for (int mb = 0; mb < 2; ++mb)
#pragma unroll
            for (int nb = 0; nb < 4; ++nb) qac[mb][nb] = (f32x4){0.f, 0.f, 0.f, 0.f};
        for (int ks = 0; ks < 8; ++ks) {
            int kb = (ks * 64 + lg * 16) ^ ((lr & 7) << 4);
            bf16x8 a0 = *(const bf16x8*)(arena + lr * 512 + kb);
            bf16x8 a1 = *(const bf16x8*)(arena + (16 + lr) * 512 + kb);
            const ushort* wq0 = wqT + ks * 32 + lg * 8;
#pragma unroll
            for (int nb = 0; nb < 4; ++nb) {
                int d = wid * 64 + nb * 16 + lr;
                bf16x8 bf = *(const bf16x8*)(wq0 + d * 256);
                qac[0][nb] = __builtin_amdgcn_mfma_f32_16x16x32_bf16(a0, bf, qac[0][nb], 0, 0, 0);
                qac[1][nb] = __builtin_amdgcn_mfma_f32_16x16x32_bf16(a1, bf, qac[1][nb], 0, 0, 0);
            }
        }
#pragma unroll
        for (int mb = 0; mb < 2; ++mb)
#pragma unroll
            for (int nb = 0; nb < 4; ++nb)
#pragma unroll
                for (int r = 0; r < 4; ++r) {
                    int m = mb * 16 + lg * 4 + r;
                    int d = wid * 64 + nb * 16 + lr;
                    *(ushort*)(arenaB + m * 512 + ((2 * d) ^ ((m & 7) << 4))) = f2bf(qac[mb][nb][r]);
                }
    }
    __syncthreads();

    // ---- Phase 3: S = Qs @ K^T (wave n-slice of 128), softmax stats, P -> arenaA
    float rinv[2][4];
    {
        f32x4 sac[2][8];
#pragma unroll
        for (int mb = 0; mb < 2; ++mb)
#pragma unroll
            for (int nb = 0; nb < 8; ++nb) sac[mb][nb] = (f32x4){0.f, 0.f, 0.f, 0.f};
        const ushort* kb16 = k16 + (size_t)b * (NCOND * DATTN);
        for (int ks = 0; ks < 8; ++ks) {
            int kb = (ks * 64 + lg * 16) ^ ((lr & 7) << 4);
            bf16x8 a0 = *(const bf16x8*)(arenaB + lr * 512 + kb);
            bf16x8 a1 = *(const bf16x8*)(arenaB + (16 + lr) * 512 + kb);
            const ushort* kp = kb16 + ks * 32 + lg * 8;
#pragma unroll
            for (int nb = 0; nb < 8; ++nb) {
                int n = wid * 128 + nb * 16 + lr;
                bf16x8 bf = *(const bf16x8*)(kp + n * 256);
                sac[0][nb] = __builtin_amdgcn_mfma_f32_16x16x32_bf16(a0, bf, sac[0][nb], 0, 0, 0);
                sac[1][nb] = __builtin_amdgcn_mfma_f32_16x16x32_bf16(a1, bf, sac[1][nb], 0, 0, 0);
            }
        }
        // per-wave row max over 128 cols
        float pmax[2][4];
#pragma unroll
        for (int mb = 0; mb < 2; ++mb)
#pragma unroll
            for (int r = 0; r < 4; ++r) {
                float m = sac[mb][0][r];
#pragma unroll
                for (int nb = 1; nb < 8; ++nb) m = fmaxf(m, sac[mb][nb][r]);
#pragma unroll
                for (int o = 8; o >= 1; o >>= 1) m = fmaxf(m, __shfl_xor(m, o));
                pmax[mb][r] = m;
            }
        if (lr == 0) {
#pragma unroll
            for (int mb = 0; mb < 2; ++mb)
#pragma unroll
                for (int r = 0; r < 4; ++r)
                    smax[(mb * 16 + lg * 4 + r) * 4 + wid] = pmax[mb][r];
        }
        __syncthreads();
        float psum[2][4];
#pragma unroll
        for (int mb = 0; mb < 2; ++mb)
#pragma unroll
            for (int r = 0; r < 4; ++r) {
                int m = mb * 16 + lg * 4 + r;
                float g = fmaxf(fmaxf(smax[m * 4], smax[m * 4 + 1]),
                                fmaxf(smax[m * 4 + 2], smax[m * 4 + 3]));
                float s = 0.f;
#pragma unroll
                for (int nb = 0; nb < 8; ++nb) {
                    float e = __expf(sac[mb][nb][r] - g);
                    s += e;
                    int n = wid * 128 + nb * 16 + lr;
                    *(ushort*)(arena + m * 1024 + ((2 * n) ^ ((m & 7) << 4))) = f2bf(e);
                }
#pragma unroll
                for (int o = 8; o >= 1; o >>= 1) s += __shfl_xor(s, o);
                psum[mb][r] = s;
            }
        if (lr == 0) {
#pragma unroll
            for (int mb = 0; mb < 2; ++mb)
#pragma unroll
                for (int r = 0; r < 4; ++r)
                    ssum[(mb * 16 + lg * 4 + r) * 4 + wid] = psum[mb][r];
        }
        __syncthreads();
#pragma unroll
        for (int mb = 0; mb < 2; ++mb)
#pragma unroll
            for (int r = 0; r < 4; ++r) {
                int m = mb * 16 + lg * 4 + r;
                rinv[mb][r] = 1.0f / (ssum[m * 4] + ssum[m * 4 + 1] + ssum[m * 4 + 2] + ssum[m * 4 + 3]);
            }
    }

    // ---- Phase 4: O = P @ V (wave d-slice of 64), scale by rinv -> Os (arenaB)
    {
        f32x4 oac[2][4];
#pragma unroll
        for (int mb = 0; mb < 2; ++mb)
#pragma unroll
            for (int nb = 0; nb < 4; ++nb) oac[mb][nb] = (f32x4){0.f, 0.f, 0.f, 0.f};
        const ushort* vb16 = vT16 + (size_t)b * (NCOND * DATTN);
        for (int ks = 0; ks < 16; ++ks) {
            int kb = (ks * 64 + lg * 16) ^ ((lr & 7) << 4);
            bf16x8 a0 = *(const bf16x8*)(arena + lr * 1024 + kb);
            bf16x8 a1 = *(const bf16x8*)(arena + (16 + lr) * 1024 + kb);
            const ushort* vp = vb16 + ks * 32 + lg * 8;
#pragma unroll
            for (int nb = 0; nb < 4; ++nb) {
                int d = wid * 64 + nb * 16 + lr;
                bf16x8 bf = *(const bf16x8*)(vp + d * 512);
                oac[0][nb] = __builtin_amdgcn_mfma_f32_16x16x32_bf16(a0, bf, oac[0][nb], 0, 0, 0);
                oac[1][nb] = __builtin_amdgcn_mfma_f32_16x16x32_bf16(a1, bf, oac[1][nb], 0, 0, 0);
            }
        }
        __syncthreads();   // P reads done; safe to overwrite arenaB (Qs dead since phase 3)
#pragma unroll
        for (int mb = 0; mb < 2; ++mb)
#pragma unroll
            for (int nb = 0; nb < 4; ++nb)
#pragma unroll
                for (int r = 0; r < 4; ++r) {
                    int m = mb * 16 + lg * 4 + r;
                    int d = wid * 64 + nb * 16 + lr;
                    *(ushort*)(arenaB + m * 512 + ((2 * d) ^ ((m & 7) << 4))) =
                        f2bf(oac[mb][nb][r] * rinv[mb][r]);
                }
    }
    __syncthreads();

    // ---- Phase 5: AF = Os @ WoT + bo -> global af (f32)
    {
        f32x4 aac[2][4];
#pragma unroll
        for (int mb = 0; mb < 2; ++mb)
#pragma unroll
            for (int nb = 0; nb < 4; ++nb) aac[mb][nb] = (f32x4){0.f, 0.f, 0.f, 0.f};
        for (int ks = 0; ks < 8; ++ks) {
            int kb = (ks * 64 + lg * 16) ^ ((lr & 7) << 4);
            bf16x8 a0 = *(const bf16x8*)(arenaB + lr * 512 + kb);
            bf16x8 a1 = *(const bf16x8*)(arenaB + (16 + lr) * 512 + kb);
            const ushort* wo0 = woT + ks * 32 + lg * 8;
#pragma unroll
            for (int nb = 0; nb < 4; ++nb) {
                int h = wid * 64 + nb * 16 + lr;
                bf16x8 bf = *(const bf16x8*)(wo0 + h * 256);
                aac[0][nb] = __builtin_amdgcn_mfma_f32_16x16x32_bf16(a0, bf, aac[0][nb], 0, 0, 0);
                aac[1][nb] = __builtin_amdgcn_mfma_f32_16x16x32_bf16(a1, bf, aac[1][nb], 0, 0, 0);
            }
        }
        size_t afbase = ((size_t)b * C + ci) * H * W;
#pragma unroll
        for (int nb = 0; nb < 4; ++nb) {
            int h = wid * 64 + nb * 16 + lr;
            float bias = bo[h];
            float* op = af + afbase + (size_t)h * W + w0;
#pragma unroll
            for (int mb = 0; mb < 2; ++mb)
#pragma unroll
                for (int r = 0; r < 4; ++r)
                    op[mb * 16 + lg * 4 + r] = aac[mb][nb][r] + bias;
        }
    }
}

// ---------------------------------------------------------------------------
// conv3x3 on cat([x*binary, attn_feature]) + bias -> raw hh into d_out.
#define CKC 32
__launch_bounds__(256)
__global__ void k_conv(const float* __restrict__ x, const float* __restrict__ af,
                       const float* __restrict__ bin, const float* __restrict__ wt,
                       const float* __restrict__ conv_b, float* __restrict__ out) {
    __shared__ float in_lds[CKC * 3 * 68];
    const int t  = threadIdx.x;
    const int blk = blockIdx.x;
    const int xt = blk & 7;
    const int y  = (blk >> 3) & 255;
    const int b  = blk >> 11;
    const int x0 = xt * 64;
    const int co = t & 127, xg = t >> 7;

    float acc[32];
#pragma unroll
    for (int j = 0; j < 32; ++j) acc[j] = 0.f;

    for (int cb = 0; cb < 2 * C; cb += CKC) {
        __syncthreads();
        for (int i = t; i < CKC * 204; i += 256) {
            int cc = i / 204; int rr = i - cc * 204;
            int yy = rr / 68; int xx = rr - yy * 68;
            if (xx < 66) {
                int cii = cb + cc;
                int iy = y + yy - 1;
                int ix = x0 + xx - 1;
                float vv = 0.f;
                if ((unsigned)iy < H && (unsigned)ix < W) {
                    if (cii < C) vv = x[((b * C + cii) * H + iy) * W + ix] * bin[iy];
                    else         vv = af[((b * C + (cii - C)) * H + iy) * W + ix];
                }
                in_lds[i] = vv;
            }
        }
        __syncthreads();
        for (int cc = 0; cc < CKC; ++cc) {
            const float* wrow = wt + (cb + cc) * 9 * 128 + co;
#pragma unroll
            for (int ky = 0; ky < 3; ++ky) {
                float w0 = wrow[(ky * 3 + 0) * 128];
                float w1 = wrow[(ky * 3 + 1) * 128];
                float w2 = wrow[(ky * 3 + 2) * 128];
                const float* row = in_lds + cc * 204 + ky * 68 + xg * 32;
#pragma unroll
                for (int jc = 0; jc < 4; ++jc) {
                    const float4* rp = (const float4*)(row + jc * 8);
                    float4 ra = rp[0], rb = rp[1];
                    float2 rc = *(const float2*)(row + jc * 8 + 8);
                    float r0 = ra.x, r1 = ra.y, r2 = ra.z, r3 = ra.w;
                    float r4 = rb.x, r5 = rb.y, r6 = rb.z, r7 = rb.w;
                    float r8 = rc.x, r9 = rc.y;
                    acc[jc * 8 + 0] += w0 * r0 + w1 * r1 + w2 * r2;
                    acc[jc * 8 + 1] += w0 * r1 + w1 * r2 + w2 * r3;
                    acc[jc * 8 + 2] += w0 * r2 + w1 * r3 + w2 * r4;
                    acc[jc * 8 + 3] += w0 * r3 + w1 * r4 + w2 * r5;
                    acc[jc * 8 + 4] += w0 * r4 + w1 * r5 + w2 * r6;
                    acc[jc * 8 + 5] += w0 * r5 + w1 * r6 + w2 * r7;
                    acc[jc * 8 + 6] += w0 * r6 + w1 * r7 + w2 * r8;
                    acc[jc * 8 + 7] += w0 * r7 + w1 * r8 + w2 * r9;
                }
            }
        }
    }
    float bias = conv_b[co];
    float* op = out + ((b * C + co) * H + y) * W + x0 + xg * 32;
#pragma unroll
    for (int j4 = 0; j4 < 8; ++j4) {
        float4 o = make_float4(acc[j4 * 4 + 0] + bias, acc[j4 * 4 + 1] + bias,
                               acc[j4 * 4 + 2] + bias, acc[j4 * 4 + 3] + bias);
        *(float4*)(op + j4 * 4) = o;
    }
}

// ---------------------------------------------------------------------------
__global__ void k_stats(const float* __restrict__ out, float* __restrict__ stats) {
    __shared__ float2 red[256];
    int blk = blockIdx.x;
    int q = blk & 3, g = (blk >> 2) & 31, b = blk >> 7;
    const float4* p = (const float4*)(out + ((b * C + g * 4) * H) * W + q * 131072);
    float s = 0.f, ss = 0.f;
    for (int i = threadIdx.x; i < 32768; i += 256) {
        float4 v = p[i];
        s  += (v.x + v.y) + (v.z + v.w);
        ss += (v.x * v.x + v.y * v.y) + (v.z * v.z + v.w * v.w);
    }
    red[threadIdx.x] = make_float2(s, ss);
    __syncthreads();
    for (int o = 128; o >= 1; o >>= 1) {
        if (threadIdx.x < o) {
            float2 a = red[threadIdx.x], c = red[threadIdx.x + o];
            red[threadIdx.x] = make_float2(a.x + c.x, a.y + c.y);
        }
        __syncthreads();
    }
    if (threadIdx.x == 0) { stats[blk * 2] = red[0].x; stats[blk * 2 + 1] = red[0].y; }
}

__global__ void k_norm(const float* __restrict__ stats, const float* __restrict__ gamma,
                       const float* __restrict__ beta, float* __restrict__ out) {
    const int N4 = B * C * H * W / 4;
    int stride = gridDim.x * 256;
    for (int i4 = blockIdx.x * 256 + threadIdx.x; i4 < N4; i4 += stride) {
        int i = i4 * 4;
        int c = (i >> 17) & 127;
        int b = i >> 24;
        int g = c >> 2;
        int sb = (b * 128 + g * 4) * 2;
        float s  = stats[sb]     + stats[sb + 2] + stats[sb + 4] + stats[sb + 6];
        float ss = stats[sb + 1] + stats[sb + 3] + stats[sb + 5] + stats[sb + 7];
        const float inv = 1.0f / 524288.0f;
        float mean = s * inv;
        float var  = ss * inv - mean * mean;
        float rstd = rsqrtf(var + 1e-6f);
        float ga = gamma[c], be = beta[c];
        float4 v = *(float4*)(out + i);
        float n0 = (v.x - mean) * rstd * ga + be;
        float n1 = (v.y - mean) * rstd * ga + be;
        float n2 = (v.z - mean) * rstd * ga + be;
        float n3 = (v.w - mean) * rstd * ga + be;
        v.x = n0 / (1.0f + __expf(-n0));
        v.y = n1 / (1.0f + __expf(-n1));
        v.z = n2 / (1.0f + __expf(-n2));
        v.w = n3 / (1.0f + __expf(-n3));
        *(float4*)(out + i) = v;
    }
}

// ---------------------------------------------------------------------------
extern "C" void kernel_launch(void* const* d_in, const int* in_sizes, int n_in,
                              void* d_out, int out_size, void* d_ws, size_t ws_size,
                              hipStream_t stream) {
    const float* x      = (const float*)d_in[0];
    const float* v      = (const float*)d_in[1];
    const float* Wq     = (const float*)d_in[2];
    const float* Wk     = (const float*)d_in[3];
    const float* Wv     = (const float*)d_in[4];
    const float* Wo     = (const float*)d_in[5];
    const float* bo     = (const float*)d_in[6];
    const float* mask_w = (const float*)d_in[7];
    const float* conv_w = (const float*)d_in[8];
    const float* conv_b = (const float*)d_in[9];
    const float* gng    = (const float*)d_in[10];
    const float* gnb    = (const float*)d_in[11];

    float* out  = (float*)d_out;
    float* mout = out + B * C * H * W;
    char*  wsb  = (char*)d_ws;
    ushort* k16  = (ushort*)(wsb + WS_K16);
    ushort* vT16 = (ushort*)(wsb + WS_VT16);
    ushort* wqT  = (ushort*)(wsb + WS_WQT);
    ushort* woT  = (ushort*)(wsb + WS_WOT);
    float* bin   = (float*)(wsb + WS_BIN);
    float* stats = (float*)(wsb + WS_STATS);
    float* wt    = (float*)(wsb + WS_WT);
    float* af    = (float*)(wsb + WS_AF);

    k_binary <<<1,    256, 0, stream>>>(mask_w, bin);
    k_maskout<<<1024, 256, 0, stream>>>(bin, mout);
    k_kv     <<<B * NCOND, 256, 0, stream>>>(v, Wk, Wv, k16, vT16);
    k_prep   <<<512,  256, 0, stream>>>(Wq, Wo, wqT, woT);
    k_wt     <<<1152, 256, 0, stream>>>(conv_w, wt);
    k_attn   <<<4096, 256, 0, stream>>>(x, k16, vT16, wqT, woT, bo, af);
    k_conv   <<<4096, 256, 0, stream>>>(x, af, bin, wt, conv_b, out);
    k_stats  <<<256,  256, 0, stream>>>(out, stats);
    k_norm   <<<2048, 256, 0, stream>>>(stats, gng, gnb, out);
}

// Round 3
// 1159.134 us; speedup vs baseline: 5.2037x; 2.5902x over previous
//
#include <hip/hip_runtime.h>
#include <math.h>

// Problem constants (from reference setup_inputs)
#define B      2
#define C      128     // channels
#define H      256     // d_model == image height
#define W      512     // image width
#define NCOND  512
#define DCOND  512
#define DATTN  256
#define KKEEP  204     // int(256 * (1 - 0.2))

// Workspace layout (byte offsets). Total ~136.1 MB (round-2 footprint proved OK).
#define WS_CATN   0ull          // bf16 NHWC cat [B][H][W][256]   134217728 B
#define WS_K16    134217728ull  // bf16 k proj [B][NCOND][DATTN]  524288 B
#define WS_VT16   134742016ull  // bf16 v proj T [B][DATTN][NCOND] 524288 B
#define WS_WQT    135266304ull  // bf16 Wq^T [d][h]               131072 B
#define WS_WOT    135397376ull  // bf16 Wo^T [h][d]               131072 B
#define WS_W9     135528448ull  // bf16 w9 [9][co=128][ci=256]    589824 B
#define WS_BIN    136118272ull  // f32 binary[256]
#define WS_STATS  136119296ull  // f32 stats[512]

typedef __attribute__((ext_vector_type(8))) short bf16x8;
typedef __attribute__((ext_vector_type(4))) float f32x4;

union U8 { bf16x8 v; ushort u[8]; };

__device__ inline ushort f2bf(float f) {
    union { float f; unsigned u; } v; v.f = f;
    unsigned r = v.u + 0x7fffu + ((v.u >> 16) & 1u);   // RNE
    return (ushort)(r >> 16);
}

// ---------------------------------------------------------------------------
// Learned mask: binary[h] = 1 iff sigmoid(mask_w[h]) is among the top-204.
__global__ void k_binary(const float* __restrict__ mask_w, float* __restrict__ bin) {
    __shared__ float s[H];
    int t = threadIdx.x;
    float sv = 1.0f / (1.0f + __expf(-mask_w[t]));
    s[t] = sv;
    __syncthreads();
    int cnt = 0;
    for (int j = 0; j < H; ++j) cnt += (s[j] > sv) ? 1 : 0;
    bin[t] = (cnt < KKEEP) ? 1.0f : 0.0f;
}

__global__ void k_maskout(const float* __restrict__ bin, float* __restrict__ mout) {
    int i = blockIdx.x * 256 + threadIdx.x;
    if (i < B * W * H) mout[i] = bin[i & (H - 1)];
}

// ---------------------------------------------------------------------------
// K/V projection -> bf16. k16: [b][n][d] row-major. vT16: [b][d][n].
__global__ void k_kv(const float* __restrict__ v, const float* __restrict__ Wk,
                     const float* __restrict__ Wv, ushort* __restrict__ k16,
                     ushort* __restrict__ vT16) {
    __shared__ float vrow[DCOND];
    int bn = blockIdx.x;              // b*NCOND + n
    int t  = threadIdx.x;             // output column e
    const float* vp = v + bn * DCOND;
    for (int i = t; i < DCOND; i += 256) vrow[i] = vp[i];
    __syncthreads();
    float ka = 0.f, va = 0.f;
    for (int d4 = 0; d4 < DCOND / 4; ++d4) {
        float4 vv = *(const float4*)(vrow + d4 * 4);
        const float* wk = Wk + (d4 * 4) * DATTN + t;
        const float* wv = Wv + (d4 * 4) * DATTN + t;
        ka += vv.x * wk[0];         va += vv.x * wv[0];
        ka += vv.y * wk[DATTN];     va += vv.y * wv[DATTN];
        ka += vv.z * wk[2 * DATTN]; va += vv.z * wv[2 * DATTN];
        ka += vv.w * wk[3 * DATTN]; va += vv.w * wv[3 * DATTN];
    }
    k16[bn * DATTN + t] = f2bf(ka);
    int b = bn >> 9, n = bn & 511;
    vT16[b * (DATTN * NCOND) + t * NCOND + n] = f2bf(va);
}

// Wq^T [d][h], Wo^T [h][d] in bf16.
__global__ void k_prep(const float* __restrict__ Wq, const float* __restrict__ Wo,
                       ushort* __restrict__ wqT, ushort* __restrict__ woT) {
    int i = blockIdx.x * 256 + threadIdx.x;
    if (i < 65536) {
        int d = i >> 8, h = i & 255;
        wqT[i] = f2bf(Wq[h * 256 + d]);
    } else {
        int j = i - 65536;
        int h = j >> 8, d = j & 255;
        woT[j] = f2bf(Wo[d * 256 + h]);
    }
}

// conv weights -> w9[p = ky*3+kx][co][ci] bf16 (K-major rows for MFMA B operand).
__global__ void k_w9(const float* __restrict__ cw, ushort* __restrict__ w9) {
    int i = blockIdx.x * 256 + threadIdx.x;
    if (i >= 9 * 128 * 256) return;
    int p  = i >> 15;
    int r  = i & 32767;
    int co = r >> 8;
    int ci = r & 255;
    w9[i] = f2bf(cw[(co * 256 + ci) * 9 + p]);
}

// ---------------------------------------------------------------------------
// Fused MFMA cross-attention (unchanged from round 2 except bf16 output).
__launch_bounds__(256)
__global__ void k_attn(const float* __restrict__ x, const ushort* __restrict__ k16,
                       const ushort* __restrict__ vT16, const ushort* __restrict__ wqT,
                       const ushort* __restrict__ woT, const float* __restrict__ bo,
                       ushort* __restrict__ af16) {
    __shared__ __align__(16) char arena[50176];
    char* arenaB = arena + 32768;
    float* smax = (float*)(arena + 49152);
    float* ssum = (float*)(arena + 49664);

    const int t   = threadIdx.x;
    const int blk = blockIdx.x;
    const int b   = blk >> 11;
    const int ci  = (blk >> 4) & 127;
    const int w0  = (blk & 15) << 5;
    const int wid = t >> 6;
    const int lr  = t & 15;
    const int lg  = (t & 63) >> 4;

    // ---- Phase 1: load X tile -> Xs[w][h] bf16 (thread t = h)
    {
        const float* xp = x + (((size_t)b * C + ci) * H + t) * W + w0;
#pragma unroll
        for (int j4 = 0; j4 < 8; ++j4) {
            float4 v4 = *(const float4*)(xp + j4 * 4);
            int j = j4 * 4;
            *(ushort*)(arena + (j + 0) * 512 + ((2 * t) ^ (((j + 0) & 7) << 4))) = f2bf(v4.x);
            *(ushort*)(arena + (j + 1) * 512 + ((2 * t) ^ (((j + 1) & 7) << 4))) = f2bf(v4.y);
            *(ushort*)(arena + (j + 2) * 512 + ((2 * t) ^ (((j + 2) & 7) << 4))) = f2bf(v4.z);
            *(ushort*)(arena + (j + 3) * 512 + ((2 * t) ^ (((j + 3) & 7) << 4))) = f2bf(v4.w);
        }
    }
    __syncthreads();

    // ---- Phase 2: Q = Xs @ WqT  -> Qs (arenaB)
    {
        f32x4 qac[2][4];
#pragma unroll
        for (int mb = 0; mb < 2; ++mb)
#pragma unroll
            for (int nb = 0; nb < 4; ++nb) qac[mb][nb] = (f32x4){0.f, 0.f, 0.f, 0.f};
        for (int ks = 0; ks < 8; ++ks) {
            int kb = (ks * 64 + lg * 16) ^ ((lr & 7) << 4);
            bf16x8 a0 = *(const bf16x8*)(arena + lr * 512 + kb);
            bf16x8 a1 = *(const bf16x8*)(arena + (16 + lr) * 512 + kb);
            const ushort* wq0 = wqT + ks * 32 + lg * 8;
#pragma unroll
            for (int nb = 0; nb < 4; ++nb) {
                int d = wid * 64 + nb * 16 + lr;
                bf16x8 bf = *(const bf16x8*)(wq0 + d * 256);
                qac[0][nb] = __builtin_amdgcn_mfma_f32_16x16x32_bf16(a0, bf, qac[0][nb], 0, 0, 0);
                qac[1][nb] = __builtin_amdgcn_mfma_f32_16x16x32_bf16(a1, bf, qac[1][nb], 0, 0, 0);
            }
        }
#pragma unroll
        for (int mb = 0; mb < 2; ++mb)
#pragma unroll
            for (int nb = 0; nb < 4; ++nb)
#pragma unroll
                for (int r = 0; r < 4; ++r) {
                    int m = mb * 16 + lg * 4 + r;
                    int d = wid * 64 + nb * 16 + lr;
                    *(ushort*)(arenaB + m * 512 + ((2 * d) ^ ((m & 7) << 4))) = f2bf(qac[mb][nb][r]);
                }
    }
    __syncthreads();

    // ---- Phase 3: S = Qs @ K^T (wave n-slice of 128), softmax stats, P -> arenaA
    float rinv[2][4];
    {
        f32x4 sac[2][8];
#pragma unroll
        for (int mb = 0; mb < 2; ++mb)
#pragma unroll
            for (int nb = 0; nb < 8; ++nb) sac[mb][nb] = (f32x4){0.f, 0.f, 0.f, 0.f};
        const ushort* kb16 = k16 + (size_t)b * (NCOND * DATTN);
        for (int ks = 0; ks < 8; ++ks) {
            int kb = (ks * 64 + lg * 16) ^ ((lr & 7) << 4);
            bf16x8 a0 = *(const bf16x8*)(arenaB + lr * 512 + kb);
            bf16x8 a1 = *(const bf16x8*)(arenaB + (16 + lr) * 512 + kb);
            const ushort* kp = kb16 + ks * 32 + lg * 8;
#pragma unroll
            for (int nb = 0; nb < 8; ++nb) {
                int n = wid * 128 + nb * 16 + lr;
                bf16x8 bf = *(const bf16x8*)(kp + n * 256);
                sac[0][nb] = __builtin_amdgcn_mfma_f32_16x16x32_bf16(a0, bf, sac[0][nb], 0, 0, 0);
                sac[1][nb] = __builtin_amdgcn_mfma_f32_16x16x32_bf16(a1, bf, sac[1][nb], 0, 0, 0);
            }
        }
        float pmax[2][4];
#pragma unroll
        for (int mb = 0; mb < 2; ++mb)
#pragma unroll
            for (int r = 0; r < 4; ++r) {
                float m = sac[mb][0][r];
#pragma unroll
                for (int nb = 1; nb < 8; ++nb) m = fmaxf(m, sac[mb][nb][r]);
#pragma unroll
                for (int o = 8; o >= 1; o >>= 1) m = fmaxf(m, __shfl_xor(m, o));
                pmax[mb][r] = m;
            }
        if (lr == 0) {
#pragma unroll
            for (int mb = 0; mb < 2; ++mb)
#pragma unroll
                for (int r = 0; r < 4; ++r)
                    smax[(mb * 16 + lg * 4 + r) * 4 + wid] = pmax[mb][r];
        }
        __syncthreads();
        float psum[2][4];
#pragma unroll
        for (int mb = 0; mb < 2; ++mb)
#pragma unroll
            for (int r = 0; r < 4; ++r) {
                int m = mb * 16 + lg * 4 + r;
                float g = fmaxf(fmaxf(smax[m * 4], smax[m * 4 + 1]),
                                fmaxf(smax[m * 4 + 2], smax[m * 4 + 3]));
                float s = 0.f;
#pragma unroll
                for (int nb = 0; nb < 8; ++nb) {
                    float e = __expf(sac[mb][nb][r] - g);
                    s += e;
                    int n = wid * 128 + nb * 16 + lr;
                    *(ushort*)(arena + m * 1024 + ((2 * n) ^ ((m & 7) << 4))) = f2bf(e);
                }
#pragma unroll
                for (int o = 8; o >= 1; o >>= 1) s += __shfl_xor(s, o);
                psum[mb][r] = s;
            }
        if (lr == 0) {
#pragma unroll
            for (int mb = 0; mb < 2; ++mb)
#pragma unroll
                for (int r = 0; r < 4; ++r)
                    ssum[(mb * 16 + lg * 4 + r) * 4 + wid] = psum[mb][r];
        }
        __syncthreads();
#pragma unroll
        for (int mb = 0; mb < 2; ++mb)
#pragma unroll
            for (int r = 0; r < 4; ++r) {
                int m = mb * 16 + lg * 4 + r;
                rinv[mb][r] = 1.0f / (ssum[m * 4] + ssum[m * 4 + 1] + ssum[m * 4 + 2] + ssum[m * 4 + 3]);
            }
    }

    // ---- Phase 4: O = P @ V (wave d-slice of 64), scale by rinv -> Os (arenaB)
    {
        f32x4 oac[2][4];
#pragma unroll
        for (int mb = 0; mb < 2; ++mb)
#pragma unroll
            for (int nb = 0; nb < 4; ++nb) oac[mb][nb] = (f32x4){0.f, 0.f, 0.f, 0.f};
        const ushort* vb16 = vT16 + (size_t)b * (NCOND * DATTN);
        for (int ks = 0; ks < 16; ++ks) {
            int kb = (ks * 64 + lg * 16) ^ ((lr & 7) << 4);
            bf16x8 a0 = *(const bf16x8*)(arena + lr * 1024 + kb);
            bf16x8 a1 = *(const bf16x8*)(arena + (16 + lr) * 1024 + kb);
            const ushort* vp = vb16 + ks * 32 + lg * 8;
#pragma unroll
            for (int nb = 0; nb < 4; ++nb) {
                int d = wid * 64 + nb * 16 + lr;
                bf16x8 bf = *(const bf16x8*)(vp + d * 512);
                oac[0][nb] = __builtin_amdgcn_mfma_f32_16x16x32_bf16(a0, bf, oac[0][nb], 0, 0, 0);
                oac[1][nb] = __builtin_amdgcn_mfma_f32_16x16x32_bf16(a1, bf, oac[1][nb], 0, 0, 0);
            }
        }
        __syncthreads();
#pragma unroll
        for (int mb = 0; mb < 2; ++mb)
#pragma unroll
            for (int nb = 0; nb < 4; ++nb)
#pragma unroll
                for (int r = 0; r < 4; ++r) {
                    int m = mb * 16 + lg * 4 + r;
                    int d = wid * 64 + nb * 16 + lr;
                    *(ushort*)(arenaB + m * 512 + ((2 * d) ^ ((m & 7) << 4))) =
                        f2bf(oac[mb][nb][r] * rinv[mb][r]);
                }
    }
    __syncthreads();

    // ---- Phase 5: AF = Os @ WoT + bo -> global af16 (bf16 NCHW)
    {
        f32x4 aac[2][4];
#pragma unroll
        for (int mb = 0; mb < 2; ++mb)
#pragma unroll
            for (int nb = 0; nb < 4; ++nb) aac[mb][nb] = (f32x4){0.f, 0.f, 0.f, 0.f};
        for (int ks = 0; ks < 8; ++ks) {
            int kb = (ks * 64 + lg * 16) ^ ((lr & 7) << 4);
            bf16x8 a0 = *(const bf16x8*)(arenaB + lr * 512 + kb);
            bf16x8 a1 = *(const bf16x8*)(arenaB + (16 + lr) * 512 + kb);
            const ushort* wo0 = woT + ks * 32 + lg * 8;
#pragma unroll
            for (int nb = 0; nb < 4; ++nb) {
                int h = wid * 64 + nb * 16 + lr;
                bf16x8 bf = *(const bf16x8*)(wo0 + h * 256);
                aac[0][nb] = __builtin_amdgcn_mfma_f32_16x16x32_bf16(a0, bf, aac[0][nb], 0, 0, 0);
                aac[1][nb] = __builtin_amdgcn_mfma_f32_16x16x32_bf16(a1, bf, aac[1][nb], 0, 0, 0);
            }
        }
        size_t afbase = ((size_t)b * C + ci) * H * W;
#pragma unroll
        for (int nb = 0; nb < 4; ++nb) {
            int h = wid * 64 + nb * 16 + lr;
            float bias = bo[h];
            ushort* op = af16 + afbase + (size_t)h * W + w0;
#pragma unroll
            for (int mb = 0; mb < 2; ++mb) {
                ushort4 u;
                u.x = f2bf(aac[mb][nb][0] + bias);
                u.y = f2bf(aac[mb][nb][1] + bias);
                u.z = f2bf(aac[mb][nb][2] + bias);
                u.w = f2bf(aac[mb][nb][3] + bias);
                *(ushort4*)(op + mb * 16 + lg * 4) = u;
            }
        }
    }
}

// ---------------------------------------------------------------------------
// Build NHWC bf16 cat: catn[b][y][x][cc] = cc<128 ? x*bin : af.
// Block = (b, y, 64-px x-tile). LDS tile [64 px][256 cc] bf16, XOR-swizzled.
__launch_bounds__(256)
__global__ void k_cat(const float* __restrict__ x, const ushort* __restrict__ af16,
                      const float* __restrict__ bin, ushort* __restrict__ catn) {
    __shared__ __align__(16) char st[32768];
    const int t   = threadIdx.x;
    const int blk = blockIdx.x;
    const int xt  = blk & 7;
    const int y   = (blk >> 3) & 255;
    const int b   = blk >> 11;
    const int x0  = xt * 64;
    const float bw = bin[y];

    // x part (cc 0..127): coalesced float4 reads, scattered ushort LDS writes
    for (int i = t; i < 2048; i += 256) {
        int cc = i >> 4, c4 = i & 15;
        float4 v = *(const float4*)(x + (((size_t)b * C + cc) * H + y) * W + x0 + c4 * 4);
#pragma unroll
        for (int j = 0; j < 4; ++j) {
            int px = c4 * 4 + j;
            float f = (j == 0 ? v.x : j == 1 ? v.y : j == 2 ? v.z : v.w) * bw;
            *(ushort*)(st + px * 512 + ((2 * cc) ^ ((px & 7) << 4))) = f2bf(f);
        }
    }
    // af part (cc 128..255): coalesced ushort8 reads
    for (int i = t; i < 1024; i += 256) {
        int cc = i >> 3, c8 = i & 7;
        U8 v;
        v.v = *(const bf16x8*)(af16 + (((size_t)b * C + cc) * H + y) * W + x0 + c8 * 8);
#pragma unroll
        for (int j = 0; j < 8; ++j) {
            int px = c8 * 8 + j;
            *(ushort*)(st + px * 512 + ((2 * (128 + cc)) ^ ((px & 7) << 4))) = v.u[j];
        }
    }
    __syncthreads();
    // write out: per px, 256 cc contiguous (512B)
    for (int i = t; i < 2048; i += 256) {
        int px = i >> 5, c16 = i & 31;
        bf16x8 v = *(const bf16x8*)(st + px * 512 + ((c16 * 16) ^ ((px & 7) << 4)));
        *(bf16x8*)(catn + (((size_t)b * H + y) * W + x0 + px) * 256 + c16 * 8) = v;
    }
}

// ---------------------------------------------------------------------------
// MFMA conv3x3 as 9 shifted GEMMs. Block = (b, y, 64-px x-tile) x all 128 co.
// 4 waves in 2x2: wave tile 32 px x 64 co. LDS = staged input row [66 px][256 cc].
__launch_bounds__(256)
__global__ void k_convm(const ushort* __restrict__ catn, const ushort* __restrict__ w9,
                        const float* __restrict__ conv_b, float* __restrict__ out) {
    __shared__ __align__(16) char st[33792];     // 66 * 512
    const int t   = threadIdx.x;
    const int blk = blockIdx.x;
    const int xt  = blk & 7;
    const int y   = (blk >> 3) & 255;
    const int b   = blk >> 11;
    const int x0  = xt * 64;
    const int wid = t >> 6;
    const int lr  = t & 15;
    const int lg  = (t & 63) >> 4;
    const int m0  = (wid >> 1) * 32;
    const int n0  = (wid & 1) * 64;

    f32x4 acc[2][4];
#pragma unroll
    for (int mb = 0; mb < 2; ++mb)
#pragma unroll
        for (int nb = 0; nb < 4; ++nb) acc[mb][nb] = (f32x4){0.f, 0.f, 0.f, 0.f};

    for (int dy = 0; dy < 3; ++dy) {
        int iy = y + dy - 1;
        bool rowok = (unsigned)iy < (unsigned)H;
        __syncthreads();
        const ushort* src = catn + ((size_t)b * H + iy) * W * 256;
        for (int i = t; i < 2112; i += 256) {      // 66 px * 32 chunks
            int px = i >> 5, c16 = i & 31;
            int gx = x0 - 1 + px;
            bf16x8 val = {0, 0, 0, 0, 0, 0, 0, 0};
            if (rowok && (unsigned)gx < (unsigned)W)
                val = *(const bf16x8*)(src + (size_t)gx * 256 + c16 * 8);
            *(bf16x8*)(st + px * 512 + ((c16 * 16) ^ ((px & 7) << 4))) = val;
        }
        __syncthreads();
#pragma unroll
        for (int dx = 0; dx < 3; ++dx) {
            const ushort* wp = w9 + (dy * 3 + dx) * 32768;
            int r0 = m0 + lr + dx;
            int r1 = r0 + 16;
#pragma unroll
            for (int ks = 0; ks < 8; ++ks) {
                int kb = ks * 64 + lg * 16;
                bf16x8 a0 = *(const bf16x8*)(st + r0 * 512 + (kb ^ ((r0 & 7) << 4)));
                bf16x8 a1 = *(const bf16x8*)(st + r1 * 512 + (kb ^ ((r1 & 7) << 4)));
#pragma unroll
                for (int nb = 0; nb < 4; ++nb) {
                    int n = n0 + nb * 16 + lr;
                    bf16x8 bf = *(const bf16x8*)(wp + n * 256 + ks * 32 + lg * 8);
                    acc[0][nb] = __builtin_amdgcn_mfma_f32_16x16x32_bf16(a0, bf, acc[0][nb], 0, 0, 0);
                    acc[1][nb] = __builtin_amdgcn_mfma_f32_16x16x32_bf16(a1, bf, acc[1][nb], 0, 0, 0);
                }
            }
        }
    }
    // epilogue: bias + f32 NCHW store (thread: n = co fixed per nb; 4 consec px)
#pragma unroll
    for (int nb = 0; nb < 4; ++nb) {
        int n = n0 + nb * 16 + lr;
        float bias = conv_b[n];
        float* op = out + (((size_t)b * C + n) * H + y) * W + x0;
#pragma unroll
        for (int mb = 0; mb < 2; ++mb) {
            int m = m0 + mb * 16 + lg * 4;
            float4 o = make_float4(acc[mb][nb][0] + bias, acc[mb][nb][1] + bias,
                                   acc[mb][nb][2] + bias, acc[mb][nb][3] + bias);
            *(float4*)(op + m) = o;
        }
    }
}

// ---------------------------------------------------------------------------
__global__ void k_stats(const float* __restrict__ out, float* __restrict__ stats) {
    __shared__ float2 red[256];
    int blk = blockIdx.x;
    int q = blk & 3, g = (blk >> 2) & 31, b = blk >> 7;
    const float4* p = (const float4*)(out + ((b * C + g * 4) * H) * W + q * 131072);
    float s = 0.f, ss = 0.f;
    for (int i = threadIdx.x; i < 32768; i += 256) {
        float4 v = p[i];
        s  += (v.x + v.y) + (v.z + v.w);
        ss += (v.x * v.x + v.y * v.y) + (v.z * v.z + v.w * v.w);
    }
    red[threadIdx.x] = make_float2(s, ss);
    __syncthreads();
    for (int o = 128; o >= 1; o >>= 1) {
        if (threadIdx.x < o) {
            float2 a = red[threadIdx.x], c = red[threadIdx.x + o];
            red[threadIdx.x] = make_float2(a.x + c.x, a.y + c.y);
        }
        __syncthreads();
    }
    if (threadIdx.x == 0) { stats[blk * 2] = red[0].x; stats[blk * 2 + 1] = red[0].y; }
}

__global__ void k_norm(const float* __restrict__ stats, const float* __restrict__ gamma,
                       const float* __restrict__ beta, float* __restrict__ out) {
    const int N4 = B * C * H * W / 4;
    int stride = gridDim.x * 256;
    for (int i4 = blockIdx.x * 256 + threadIdx.x; i4 < N4; i4 += stride) {
        int i = i4 * 4;
        int c = (i >> 17) & 127;
        int b = i >> 24;
        int g = c >> 2;
        int sb = (b * 128 + g * 4) * 2;
        float s  = stats[sb]     + stats[sb + 2] + stats[sb + 4] + stats[sb + 6];
        float ss = stats[sb + 1] + stats[sb + 3] + stats[sb + 5] + stats[sb + 7];
        const float inv = 1.0f / 524288.0f;
        float mean = s * inv;
        float var  = ss * inv - mean * mean;
        float rstd = rsqrtf(var + 1e-6f);
        float ga = gamma[c], be = beta[c];
        float4 v = *(float4*)(out + i);
        float n0 = (v.x - mean) * rstd * ga + be;
        float n1 = (v.y - mean) * rstd * ga + be;
        float n2 = (v.z - mean) * rstd * ga + be;
        float n3 = (v.w - mean) * rstd * ga + be;
        v.x = n0 / (1.0f + __expf(-n0));
        v.y = n1 / (1.0f + __expf(-n1));
        v.z = n2 / (1.0f + __expf(-n2));
        v.w = n3 / (1.0f + __expf(-n3));
        *(float4*)(out + i) = v;
    }
}

// ---------------------------------------------------------------------------
extern "C" void kernel_launch(void* const* d_in, const int* in_sizes, int n_in,
                              void* d_out, int out_size, void* d_ws, size_t ws_size,
                              hipStream_t stream) {
    const float* x      = (const float*)d_in[0];
    const float* v      = (const float*)d_in[1];
    const float* Wq     = (const float*)d_in[2];
    const float* Wk     = (const float*)d_in[3];
    const float* Wv     = (const float*)d_in[4];
    const float* Wo     = (const float*)d_in[5];
    const float* bo     = (const float*)d_in[6];
    const float* mask_w = (const float*)d_in[7];
    const float* conv_w = (const float*)d_in[8];
    const float* conv_b = (const float*)d_in[9];
    const float* gng    = (const float*)d_in[10];
    const float* gnb    = (const float*)d_in[11];

    float* out  = (float*)d_out;
    float* mout = out + B * C * H * W;
    // d_out's 134 MB out-region is dead until k_convm writes it -> use its
    // first 67 MB as bf16 scratch for the attention feature (consumed by k_cat
    // strictly before k_convm overwrites; stream-ordered, deterministic).
    ushort* af16 = (ushort*)d_out;

    char*  wsb  = (char*)d_ws;
    ushort* catn = (ushort*)(wsb + WS_CATN);
    ushort* k16  = (ushort*)(wsb + WS_K16);
    ushort* vT16 = (ushort*)(wsb + WS_VT16);
    ushort* wqT  = (ushort*)(wsb + WS_WQT);
    ushort* woT  = (ushort*)(wsb + WS_WOT);
    ushort* w9   = (ushort*)(wsb + WS_W9);
    float* bin   = (float*)(wsb + WS_BIN);
    float* stats = (float*)(wsb + WS_STATS);

    k_binary <<<1,    256, 0, stream>>>(mask_w, bin);
    k_maskout<<<1024, 256, 0, stream>>>(bin, mout);
    k_kv     <<<B * NCOND, 256, 0, stream>>>(v, Wk, Wv, k16, vT16);
    k_prep   <<<512,  256, 0, stream>>>(Wq, Wo, wqT, woT);
    k_w9     <<<1152, 256, 0, stream>>>(conv_w, w9);
    k_attn   <<<4096, 256, 0, stream>>>(x, k16, vT16, wqT, woT, bo, af16);
    k_cat    <<<4096, 256, 0, stream>>>(x, af16, bin, catn);
    k_convm  <<<4096, 256, 0, stream>>>(catn, w9, conv_b, out);
    k_stats  <<<256,  256, 0, stream>>>(out, stats);
    k_norm   <<<2048, 256, 0, stream>>>(stats, gng, gnb, out);
}

// Round 4
// 1021.812 us; speedup vs baseline: 5.9030x; 1.1344x over previous
//
#include <hip/hip_runtime.h>
#include <math.h>

// Problem constants (from reference setup_inputs)
#define B      2
#define C      128     // channels
#define H      256     // d_model == image height
#define W      512     // image width
#define NCOND  512
#define DCOND  512
#define DATTN  256
#define KKEEP  204     // int(256 * (1 - 0.2))

// Workspace layout (byte offsets). Total ~70.1 MB.
#define WS_AF     0ull          // bf16 attn feature NCHW [B][C][H][W]  67108864 B
#define WS_K16    67108864ull   // bf16 k proj [B][NCOND][DATTN]        524288 B
#define WS_VT16   67633152ull   // bf16 v proj T [B][DATTN][NCOND]      524288 B
#define WS_WQT    68157440ull   // bf16 Wq^T [d][h]                     131072 B
#define WS_WOT    68288512ull   // bf16 Wo^T [h][d]                     131072 B
#define WS_W9     68419584ull   // bf16 w9 [9][co=128][ci=256]          589824 B
#define WS_BIN    69009408ull   // f32 binary[256]
#define WS_PB     69010432ull   // f32 per-block GN partials [4096][32][2] = 1 MB
#define WS_ST2    70059008ull   // f32 final stats [B][32][2] (mean, rstd)

typedef __attribute__((ext_vector_type(8))) short bf16x8;
typedef __attribute__((ext_vector_type(4))) float f32x4;

union U8 { bf16x8 v; ushort u[8]; };

__device__ inline ushort f2bf(float f) {
    union { float f; unsigned u; } v; v.f = f;
    unsigned r = v.u + 0x7fffu + ((v.u >> 16) & 1u);   // RNE
    return (ushort)(r >> 16);
}

// ---------------------------------------------------------------------------
// Learned mask: binary[h] = 1 iff sigmoid(mask_w[h]) is among the top-204.
__global__ void k_binary(const float* __restrict__ mask_w, float* __restrict__ bin) {
    __shared__ float s[H];
    int t = threadIdx.x;
    float sv = 1.0f / (1.0f + __expf(-mask_w[t]));
    s[t] = sv;
    __syncthreads();
    int cnt = 0;
    for (int j = 0; j < H; ++j) cnt += (s[j] > sv) ? 1 : 0;
    bin[t] = (cnt < KKEEP) ? 1.0f : 0.0f;
}

__global__ void k_maskout(const float* __restrict__ bin, float* __restrict__ mout) {
    int i = blockIdx.x * 256 + threadIdx.x;
    if (i < B * W * H) mout[i] = bin[i & (H - 1)];
}

// ---------------------------------------------------------------------------
// K/V projection -> bf16. k16: [b][n][d] row-major. vT16: [b][d][n].
__global__ void k_kv(const float* __restrict__ v, const float* __restrict__ Wk,
                     const float* __restrict__ Wv, ushort* __restrict__ k16,
                     ushort* __restrict__ vT16) {
    __shared__ float vrow[DCOND];
    int bn = blockIdx.x;              // b*NCOND + n
    int t  = threadIdx.x;             // output column e
    const float* vp = v + bn * DCOND;
    for (int i = t; i < DCOND; i += 256) vrow[i] = vp[i];
    __syncthreads();
    float ka = 0.f, va = 0.f;
    for (int d4 = 0; d4 < DCOND / 4; ++d4) {
        float4 vv = *(const float4*)(vrow + d4 * 4);
        const float* wk = Wk + (d4 * 4) * DATTN + t;
        const float* wv = Wv + (d4 * 4) * DATTN + t;
        ka += vv.x * wk[0];         va += vv.x * wv[0];
        ka += vv.y * wk[DATTN];     va += vv.y * wv[DATTN];
        ka += vv.z * wk[2 * DATTN]; va += vv.z * wv[2 * DATTN];
        ka += vv.w * wk[3 * DATTN]; va += vv.w * wv[3 * DATTN];
    }
    k16[bn * DATTN + t] = f2bf(ka);
    int b = bn >> 9, n = bn & 511;
    vT16[b * (DATTN * NCOND) + t * NCOND + n] = f2bf(va);
}

// Wq^T [d][h], Wo^T [h][d] in bf16.
__global__ void k_prep(const float* __restrict__ Wq, const float* __restrict__ Wo,
                       ushort* __restrict__ wqT, ushort* __restrict__ woT) {
    int i = blockIdx.x * 256 + threadIdx.x;
    if (i < 65536) {
        int d = i >> 8, h = i & 255;
        wqT[i] = f2bf(Wq[h * 256 + d]);
    } else {
        int j = i - 65536;
        int h = j >> 8, d = j & 255;
        woT[j] = f2bf(Wo[d * 256 + h]);
    }
}

// conv weights -> w9[p = ky*3+kx][co][ci] bf16 (K-major rows for MFMA B operand).
__global__ void k_w9(const float* __restrict__ cw, ushort* __restrict__ w9) {
    int i = blockIdx.x * 256 + threadIdx.x;
    if (i >= 9 * 128 * 256) return;
    int p  = i >> 15;
    int r  = i & 32767;
    int co = r >> 8;
    int ci = r & 255;
    w9[i] = f2bf(cw[(co * 256 + ci) * 9 + p]);
}

// ---------------------------------------------------------------------------
// Fused MFMA cross-attention (round-2 structure, bf16 output into ws).
__launch_bounds__(256)
__global__ void k_attn(const float* __restrict__ x, const ushort* __restrict__ k16,
                       const ushort* __restrict__ vT16, const ushort* __restrict__ wqT,
                       const ushort* __restrict__ woT, const float* __restrict__ bo,
                       ushort* __restrict__ af16) {
    __shared__ __align__(16) char arena[50176];
    char* arenaB = arena + 32768;
    float* smax = (float*)(arena + 49152);
    float* ssum = (float*)(arena + 49664);

    const int t   = threadIdx.x;
    const int blk = blockIdx.x;
    const int b   = blk >> 11;
    const int ci  = (blk >> 4) & 127;
    const int w0  = (blk & 15) << 5;
    const int wid = t >> 6;
    const int lr  = t & 15;
    const int lg  = (t & 63) >> 4;

    // ---- Phase 1: load X tile -> Xs[w][h] bf16 (thread t = h)
    {
        const float* xp = x + (((size_t)b * C + ci) * H + t) * W + w0;
#pragma unroll
        for (int j4 = 0; j4 < 8; ++j4) {
            float4 v4 = *(const float4*)(xp + j4 * 4);
            int j = j4 * 4;
            *(ushort*)(arena + (j + 0) * 512 + ((2 * t) ^ (((j + 0) & 7) << 4))) = f2bf(v4.x);
            *(ushort*)(arena + (j + 1) * 512 + ((2 * t) ^ (((j + 1) & 7) << 4))) = f2bf(v4.y);
            *(ushort*)(arena + (j + 2) * 512 + ((2 * t) ^ (((j + 2) & 7) << 4))) = f2bf(v4.z);
            *(ushort*)(arena + (j + 3) * 512 + ((2 * t) ^ (((j + 3) & 7) << 4))) = f2bf(v4.w);
        }
    }
    __syncthreads();

    // ---- Phase 2: Q = Xs @ WqT  -> Qs (arenaB)
    {
        f32x4 qac[2][4];
#pragma unroll
        for (int mb = 0; mb < 2; ++mb)
#pragma unroll
            for (int nb = 0; nb < 4; ++nb) qac[mb][nb] = (f32x4){0.f, 0.f, 0.f, 0.f};
        for (int ks = 0; ks < 8; ++ks) {
            int kb = (ks * 64 + lg * 16) ^ ((lr & 7) << 4);
            bf16x8 a0 = *(const bf16x8*)(arena + lr * 512 + kb);
            bf16x8 a1 = *(const bf16x8*)(arena + (16 + lr) * 512 + kb);
            const ushort* wq0 = wqT + ks * 32 + lg * 8;
#pragma unroll
            for (int nb = 0; nb < 4; ++nb) {
                int d = wid * 64 + nb * 16 + lr;
                bf16x8 bf = *(const bf16x8*)(wq0 + d * 256);
                qac[0][nb] = __builtin_amdgcn_mfma_f32_16x16x32_bf16(a0, bf, qac[0][nb], 0, 0, 0);
                qac[1][nb] = __builtin_amdgcn_mfma_f32_16x16x32_bf16(a1, bf, qac[1][nb], 0, 0, 0);
            }
        }
#pragma unroll
        for (int mb = 0; mb < 2; ++mb)
#pragma unroll
            for (int nb = 0; nb < 4; ++nb)
#pragma unroll
                for (int r = 0; r < 4; ++r) {
                    int m = mb * 16 + lg * 4 + r;
                    int d = wid * 64 + nb * 16 + lr;
                    *(ushort*)(arenaB + m * 512 + ((2 * d) ^ ((m & 7) << 4))) = f2bf(qac[mb][nb][r]);
                }
    }
    __syncthreads();

    // ---- Phase 3: S = Qs @ K^T (wave n-slice of 128), softmax stats, P -> arenaA
    float rinv[2][4];
    {
        f32x4 sac[2][8];
#pragma unroll
        for (int mb = 0; mb < 2; ++mb)
#pragma unroll
            for (int nb = 0; nb < 8; ++nb) sac[mb][nb] = (f32x4){0.f, 0.f, 0.f, 0.f};
        const ushort* kb16 = k16 + (size_t)b * (NCOND * DATTN);
        for (int ks = 0; ks < 8; ++ks) {
            int kb = (ks * 64 + lg * 16) ^ ((lr & 7) << 4);
            bf16x8 a0 = *(const bf16x8*)(arenaB + lr * 512 + kb);
            bf16x8 a1 = *(const bf16x8*)(arenaB + (16 + lr) * 512 + kb);
            const ushort* kp = kb16 + ks * 32 + lg * 8;
#pragma unroll
            for (int nb = 0; nb < 8; ++nb) {
                int n = wid * 128 + nb * 16 + lr;
                bf16x8 bf = *(const bf16x8*)(kp + n * 256);
                sac[0][nb] = __builtin_amdgcn_mfma_f32_16x16x32_bf16(a0, bf, sac[0][nb], 0, 0, 0);
                sac[1][nb] = __builtin_amdgcn_mfma_f32_16x16x32_bf16(a1, bf, sac[1][nb], 0, 0, 0);
            }
        }
        float pmax[2][4];
#pragma unroll
        for (int mb = 0; mb < 2; ++mb)
#pragma unroll
            for (int r = 0; r < 4; ++r) {
                float m = sac[mb][0][r];
#pragma unroll
                for (int nb = 1; nb < 8; ++nb) m = fmaxf(m, sac[mb][nb][r]);
#pragma unroll
                for (int o = 8; o >= 1; o >>= 1) m = fmaxf(m, __shfl_xor(m, o));
                pmax[mb][r] = m;
            }
        if (lr == 0) {
#pragma unroll
            for (int mb = 0; mb < 2; ++mb)
#pragma unroll
                for (int r = 0; r < 4; ++r)
                    smax[(mb * 16 + lg * 4 + r) * 4 + wid] = pmax[mb][r];
        }
        __syncthreads();
        float psum[2][4];
#pragma unroll
        for (int mb = 0; mb < 2; ++mb)
#pragma unroll
            for (int r = 0; r < 4; ++r) {
                int m = mb * 16 + lg * 4 + r;
                float g = fmaxf(fmaxf(smax[m * 4], smax[m * 4 + 1]),
                                fmaxf(smax[m * 4 + 2], smax[m * 4 + 3]));
                float s = 0.f;
#pragma unroll
                for (int nb = 0; nb < 8; ++nb) {
                    float e = __expf(sac[mb][nb][r] - g);
                    s += e;
                    int n = wid * 128 + nb * 16 + lr;
                    *(ushort*)(arena + m * 1024 + ((2 * n) ^ ((m & 7) << 4))) = f2bf(e);
                }
#pragma unroll
                for (int o = 8; o >= 1; o >>= 1) s += __shfl_xor(s, o);
                psum[mb][r] = s;
            }
        if (lr == 0) {
#pragma unroll
            for (int mb = 0; mb < 2; ++mb)
#pragma unroll
                for (int r = 0; r < 4; ++r)
                    ssum[(mb * 16 + lg * 4 + r) * 4 + wid] = psum[mb][r];
        }
        __syncthreads();
#pragma unroll
        for (int mb = 0; mb < 2; ++mb)
#pragma unroll
            for (int r = 0; r < 4; ++r) {
                int m = mb * 16 + lg * 4 + r;
                rinv[mb][r] = 1.0f / (ssum[m * 4] + ssum[m * 4 + 1] + ssum[m * 4 + 2] + ssum[m * 4 + 3]);
            }
    }

    // ---- Phase 4: O = P @ V (wave d-slice of 64), scale by rinv -> Os (arenaB)
    {
        f32x4 oac[2][4];
#pragma unroll
        for (int mb = 0; mb < 2; ++mb)
#pragma unroll
            for (int nb = 0; nb < 4; ++nb) oac[mb][nb] = (f32x4){0.f, 0.f, 0.f, 0.f};
        const ushort* vb16 = vT16 + (size_t)b * (NCOND * DATTN);
        for (int ks = 0; ks < 16; ++ks) {
            int kb = (ks * 64 + lg * 16) ^ ((lr & 7) << 4);
            bf16x8 a0 = *(const bf16x8*)(arena + lr * 1024 + kb);
            bf16x8 a1 = *(const bf16x8*)(arena + (16 + lr) * 1024 + kb);
            const ushort* vp = vb16 + ks * 32 + lg * 8;
#pragma unroll
            for (int nb = 0; nb < 4; ++nb) {
                int d = wid * 64 + nb * 16 + lr;
                bf16x8 bf = *(const bf16x8*)(vp + d * 512);
                oac[0][nb] = __builtin_amdgcn_mfma_f32_16x16x32_bf16(a0, bf, oac[0][nb], 0, 0, 0);
                oac[1][nb] = __builtin_amdgcn_mfma_f32_16x16x32_bf16(a1, bf, oac[1][nb], 0, 0, 0);
            }
        }
        __syncthreads();
#pragma unroll
        for (int mb = 0; mb < 2; ++mb)
#pragma unroll
            for (int nb = 0; nb < 4; ++nb)
#pragma unroll
                for (int r = 0; r < 4; ++r) {
                    int m = mb * 16 + lg * 4 + r;
                    int d = wid * 64 + nb * 16 + lr;
                    *(ushort*)(arenaB + m * 512 + ((2 * d) ^ ((m & 7) << 4))) =
                        f2bf(oac[mb][nb][r] * rinv[mb][r]);
                }
    }
    __syncthreads();

    // ---- Phase 5: AF = Os @ WoT + bo -> af16 (bf16 NCHW, in ws)
    {
        f32x4 aac[2][4];
#pragma unroll
        for (int mb = 0; mb < 2; ++mb)
#pragma unroll
            for (int nb = 0; nb < 4; ++nb) aac[mb][nb] = (f32x4){0.f, 0.f, 0.f, 0.f};
        for (int ks = 0; ks < 8; ++ks) {
            int kb = (ks * 64 + lg * 16) ^ ((lr & 7) << 4);
            bf16x8 a0 = *(const bf16x8*)(arenaB + lr * 512 + kb);
            bf16x8 a1 = *(const bf16x8*)(arenaB + (16 + lr) * 512 + kb);
            const ushort* wo0 = woT + ks * 32 + lg * 8;
#pragma unroll
            for (int nb = 0; nb < 4; ++nb) {
                int h = wid * 64 + nb * 16 + lr;
                bf16x8 bf = *(const bf16x8*)(wo0 + h * 256);
                aac[0][nb] = __builtin_amdgcn_mfma_f32_16x16x32_bf16(a0, bf, aac[0][nb], 0, 0, 0);
                aac[1][nb] = __builtin_amdgcn_mfma_f32_16x16x32_bf16(a1, bf, aac[1][nb], 0, 0, 0);
            }
        }
        size_t afbase = ((size_t)b * C + ci) * H * W;
#pragma unroll
        for (int nb = 0; nb < 4; ++nb) {
            int h = wid * 64 + nb * 16 + lr;
            float bias = bo[h];
            ushort* op = af16 + afbase + (size_t)h * W + w0;
#pragma unroll
            for (int mb = 0; mb < 2; ++mb) {
                ushort4 u;
                u.x = f2bf(aac[mb][nb][0] + bias);
                u.y = f2bf(aac[mb][nb][1] + bias);
                u.z = f2bf(aac[mb][nb][2] + bias);
                u.w = f2bf(aac[mb][nb][3] + bias);
                *(ushort4*)(op + mb * 16 + lg * 4) = u;
            }
        }
    }
}

// ---------------------------------------------------------------------------
// Fused cat + conv3x3 + GN-partials. Block = (b, y, 64-px x-tile), all 128 co.
// 4 waves, each 64 px (M) x 32 co (N): no duplicate weight loads, B reused 4x.
// LDS st = one input row [66 px][256 cc] bf16, XOR-swizzled; built on the fly
// from x (*bin) and af16 (the concat transpose fused in).
__launch_bounds__(256)
__global__ void k_convf(const float* __restrict__ x, const ushort* __restrict__ af16,
                        const float* __restrict__ bin, const ushort* __restrict__ w9,
                        const float* __restrict__ conv_b, float* __restrict__ out,
                        float* __restrict__ pb) {
    __shared__ __align__(16) char st[33792];     // 66 * 512
    __shared__ float pst[64];                    // 32 groups * (sum, sumsq)
    const int t   = threadIdx.x;
    const int blk = blockIdx.x;
    const int xt  = blk & 7;
    const int y   = (blk >> 3) & 255;
    const int b   = blk >> 11;
    const int x0  = xt * 64;
    const int wid = t >> 6;
    const int lr  = t & 15;
    const int lg  = (t & 63) >> 4;
    const int n0  = wid * 32;                    // wave's co slice

    f32x4 acc[4][2];
#pragma unroll
    for (int mb = 0; mb < 4; ++mb)
#pragma unroll
        for (int nb = 0; nb < 2; ++nb) acc[mb][nb] = (f32x4){0.f, 0.f, 0.f, 0.f};

    for (int dy = 0; dy < 3; ++dy) {
        const int iy = y + dy - 1;
        const bool rowok = (unsigned)iy < (unsigned)H;
        const float bw = rowok ? bin[iy] : 0.f;
        __syncthreads();
        // ---- stage row iy: [66 px][256 cc] with fused concat transpose
        {
            const size_t xrow  = rowok ? ((((size_t)b * C) * H + iy) * W) : 0;  // + cc*H*W
            // x part, px 1..64 (f32x4 coalesced per cc)
#pragma unroll
            for (int it = 0; it < 8; ++it) {
                int i = t + it * 256;            // 0..2047
                int cc = i >> 4, ch = i & 15;
                float4 v = make_float4(0.f, 0.f, 0.f, 0.f);
                if (rowok) v = *(const float4*)(x + xrow + (size_t)cc * H * W + x0 + ch * 4);
#pragma unroll
                for (int j = 0; j < 4; ++j) {
                    int px = 1 + ch * 4 + j;
                    float f = (j == 0 ? v.x : j == 1 ? v.y : j == 2 ? v.z : v.w) * bw;
                    *(ushort*)(st + px * 512 + ((2 * cc) ^ ((px & 7) << 4))) = f2bf(f);
                }
            }
            // x edges (px 0 and 65)
            {
                int cc = t >> 1, side = t & 1;
                int px = side * 65;
                int gx = x0 - 1 + px;
                float f = 0.f;
                if (rowok && (unsigned)gx < (unsigned)W)
                    f = x[xrow + (size_t)cc * H * W + gx] * bw;
                *(ushort*)(st + px * 512 + ((2 * cc) ^ ((px & 7) << 4))) = f2bf(f);
            }
            // af part, px 1..64 (bf16x8 coalesced per cc)
#pragma unroll
            for (int it = 0; it < 4; ++it) {
                int i = t + it * 256;            // 0..1023
                int cc = i >> 3, ch = i & 7;
                U8 v; v.v = (bf16x8){0, 0, 0, 0, 0, 0, 0, 0};
                if (rowok) v.v = *(const bf16x8*)(af16 + xrow + (size_t)cc * H * W + x0 + ch * 8);
#pragma unroll
                for (int j = 0; j < 8; ++j) {
                    int px = 1 + ch * 8 + j;
                    *(ushort*)(st + px * 512 + ((2 * (128 + cc)) ^ ((px & 7) << 4))) = v.u[j];
                }
            }
            // af edges
            {
                int cc = t >> 1, side = t & 1;
                int px = side * 65;
                int gx = x0 - 1 + px;
                ushort u = 0;
                if (rowok && (unsigned)gx < (unsigned)W)
                    u = af16[xrow + (size_t)cc * H * W + gx];
                *(ushort*)(st + px * 512 + ((2 * (128 + cc)) ^ ((px & 7) << 4))) = u;
            }
        }
        __syncthreads();
        // ---- compute: 3 dx, weights batched into regs per dx (16 frags = 64 VGPR)
#pragma unroll
        for (int dx = 0; dx < 3; ++dx) {
            const ushort* wp = w9 + (dy * 3 + dx) * 32768 + (size_t)(n0 + lr) * 256 + lg * 8;
            bf16x8 bfr[2][8];
#pragma unroll
            for (int nb = 0; nb < 2; ++nb)
#pragma unroll
                for (int ks = 0; ks < 8; ++ks)
                    bfr[nb][ks] = *(const bf16x8*)(wp + nb * 16 * 256 + ks * 32);
#pragma unroll
            for (int ks = 0; ks < 8; ++ks) {
                int kb = ks * 64 + lg * 16;
                bf16x8 a[4];
#pragma unroll
                for (int mb = 0; mb < 4; ++mb) {
                    int r = mb * 16 + lr + dx;
                    a[mb] = *(const bf16x8*)(st + r * 512 + (kb ^ ((r & 7) << 4)));
                }
#pragma unroll
                for (int nb = 0; nb < 2; ++nb)
#pragma unroll
                    for (int mb = 0; mb < 4; ++mb)
                        acc[mb][nb] = __builtin_amdgcn_mfma_f32_16x16x32_bf16(a[mb], bfr[nb][ks], acc[mb][nb], 0, 0, 0);
            }
        }
    }

    // ---- epilogue: bias, store f32 NCHW, and per-group (sum, sumsq) partials
#pragma unroll
    for (int nb = 0; nb < 2; ++nb) {
        int co = n0 + nb * 16 + lr;
        float bias = conv_b[co];
        float s = 0.f, ss = 0.f;
        float* op = out + (((size_t)b * C + co) * H + y) * W + x0;
#pragma unroll
        for (int mb = 0; mb < 4; ++mb) {
            float4 o = make_float4(acc[mb][nb][0] + bias, acc[mb][nb][1] + bias,
                                   acc[mb][nb][2] + bias, acc[mb][nb][3] + bias);
            s  += (o.x + o.y) + (o.z + o.w);
            ss += (o.x * o.x + o.y * o.y) + (o.z * o.z + o.w * o.w);
            *(float4*)(op + mb * 16 + lg * 4) = o;
        }
        // reduce over lanes sharing the co-group: lr^1, lr^2 (4 co per group),
        // then lg (xor 16, 32) to sum the px dimension.
        s += __shfl_xor(s, 1);  ss += __shfl_xor(ss, 1);
        s += __shfl_xor(s, 2);  ss += __shfl_xor(ss, 2);
        s += __shfl_xor(s, 16); ss += __shfl_xor(ss, 16);
        s += __shfl_xor(s, 32); ss += __shfl_xor(ss, 32);
        if (lg == 0 && (lr & 3) == 0) {
            int g = co >> 2;                     // distinct per (wave, nb, lr>>2)
            pst[g * 2]     = s;
            pst[g * 2 + 1] = ss;
        }
    }
    __syncthreads();
    if (t < 64) pb[(size_t)blk * 64 + t] = pst[t];
}

// ---------------------------------------------------------------------------
// Reduce per-block GN partials -> mean/rstd per (b, group). 64 blocks.
__global__ void k_stats2(const float* __restrict__ pb, float* __restrict__ st2) {
    __shared__ float red[512];
    int blk = blockIdx.x;            // b*32 + g
    int b = blk >> 5, g = blk & 31;
    int t = threadIdx.x;
    float s = 0.f, ss = 0.f;
    for (int j = t; j < 2048; j += 256) {
        const float* p = pb + ((size_t)(b * 2048 + j)) * 64 + g * 2;
        s += p[0]; ss += p[1];
    }
    red[t * 2] = s; red[t * 2 + 1] = ss;
    __syncthreads();
    for (int o = 128; o >= 1; o >>= 1) {
        if (t < o) {
            red[t * 2]     += red[(t + o) * 2];
            red[t * 2 + 1] += red[(t + o) * 2 + 1];
        }
        __syncthreads();
    }
    if (t == 0) {
        const float inv = 1.0f / 524288.0f;     // 4 ch * 256 * 512
        float mean = red[0] * inv;
        float var  = red[1] * inv - mean * mean;
        st2[blk * 2]     = mean;
        st2[blk * 2 + 1] = rsqrtf(var + 1e-6f);
    }
}

// GroupNorm normalize + affine + SiLU, in place on d_out.
__global__ void k_norm(const float* __restrict__ st2, const float* __restrict__ gamma,
                       const float* __restrict__ beta, float* __restrict__ out) {
    const int N4 = B * C * H * W / 4;
    int stride = gridDim.x * 256;
    for (int i4 = blockIdx.x * 256 + threadIdx.x; i4 < N4; i4 += stride) {
        int i = i4 * 4;
        int c = (i >> 17) & 127;
        int b = i >> 24;
        int g = c >> 2;
        float mean = st2[(b * 32 + g) * 2];
        float rstd = st2[(b * 32 + g) * 2 + 1];
        float ga = gamma[c], be = beta[c];
        float4 v = *(float4*)(out + i);
        float n0 = (v.x - mean) * rstd * ga + be;
        float n1 = (v.y - mean) * rstd * ga + be;
        float n2 = (v.z - mean) * rstd * ga + be;
        float n3 = (v.w - mean) * rstd * ga + be;
        v.x = n0 / (1.0f + __expf(-n0));
        v.y = n1 / (1.0f + __expf(-n1));
        v.z = n2 / (1.0f + __expf(-n2));
        v.w = n3 / (1.0f + __expf(-n3));
        *(float4*)(out + i) = v;
    }
}

// ---------------------------------------------------------------------------
extern "C" void kernel_launch(void* const* d_in, const int* in_sizes, int n_in,
                              void* d_out, int out_size, void* d_ws, size_t ws_size,
                              hipStream_t stream) {
    const float* x      = (const float*)d_in[0];
    const float* v      = (const float*)d_in[1];
    const float* Wq     = (const float*)d_in[2];
    const float* Wk     = (const float*)d_in[3];
    const float* Wv     = (const float*)d_in[4];
    const float* Wo     = (const float*)d_in[5];
    const float* bo     = (const float*)d_in[6];
    const float* mask_w = (const float*)d_in[7];
    const float* conv_w = (const float*)d_in[8];
    const float* conv_b = (const float*)d_in[9];
    const float* gng    = (const float*)d_in[10];
    const float* gnb    = (const float*)d_in[11];

    float* out  = (float*)d_out;
    float* mout = out + B * C * H * W;

    char*  wsb  = (char*)d_ws;
    ushort* af16 = (ushort*)(wsb + WS_AF);
    ushort* k16  = (ushort*)(wsb + WS_K16);
    ushort* vT16 = (ushort*)(wsb + WS_VT16);
    ushort* wqT  = (ushort*)(wsb + WS_WQT);
    ushort* woT  = (ushort*)(wsb + WS_WOT);
    ushort* w9   = (ushort*)(wsb + WS_W9);
    float* bin   = (float*)(wsb + WS_BIN);
    float* pb    = (float*)(wsb + WS_PB);
    float* st2   = (float*)(wsb + WS_ST2);

    k_binary <<<1,    256, 0, stream>>>(mask_w, bin);
    k_maskout<<<1024, 256, 0, stream>>>(bin, mout);
    k_kv     <<<B * NCOND, 256, 0, stream>>>(v, Wk, Wv, k16, vT16);
    k_prep   <<<512,  256, 0, stream>>>(Wq, Wo, wqT, woT);
    k_w9     <<<1152, 256, 0, stream>>>(conv_w, w9);
    k_attn   <<<4096, 256, 0, stream>>>(x, k16, vT16, wqT, woT, bo, af16);
    k_convf  <<<4096, 256, 0, stream>>>(x, af16, bin, w9, conv_b, out, pb);
    k_stats2 <<<64,   256, 0, stream>>>(pb, st2);
    k_norm   <<<2048, 256, 0, stream>>>(st2, gng, gnb, out);
}

// Round 5
// 923.192 us; speedup vs baseline: 6.5336x; 1.1068x over previous
//
#include <hip/hip_runtime.h>
#include <math.h>

// Problem constants (from reference setup_inputs)
#define B      2
#define C      128     // channels
#define H      256     // d_model == image height
#define W      512     // image width
#define NCOND  512
#define DCOND  512
#define DATTN  256
#define KKEEP  204     // int(256 * (1 - 0.2))

// Workspace layout (byte offsets). Total ~136.12 MB (== round-3 proven footprint).
#define WS_CATN   0ull          // bf16 NHWC cat [B][H][W][256]   134217728 B
#define WS_K16    134217728ull  // bf16 k proj [B][NCOND][DATTN]  524288 B
#define WS_VT16   134742016ull  // bf16 v proj T [B][DATTN][NCOND] 524288 B
#define WS_WQT    135266304ull  // bf16 Wq^T [d][h]               131072 B  (reused as pb after attn)
#define WS_WOT    135397376ull  // bf16 Wo^T [h][d]               131072 B  (reused as pb after attn)
#define WS_W9     135528448ull  // bf16 w9 [9][co=128][ci=256]    589824 B
#define WS_BIN    136118272ull  // f32 binary[256]                1024 B
#define WS_ST2    136119296ull  // f32 final stats [B][32][2]     512 B

typedef __attribute__((ext_vector_type(8))) short bf16x8;
typedef __attribute__((ext_vector_type(4))) float f32x4;

union U8 { bf16x8 v; ushort u[8]; };

__device__ inline ushort f2bf(float f) {
    union { float f; unsigned u; } v; v.f = f;
    unsigned r = v.u + 0x7fffu + ((v.u >> 16) & 1u);   // RNE
    return (ushort)(r >> 16);
}

// ---------------------------------------------------------------------------
// Learned mask: binary[h] = 1 iff sigmoid(mask_w[h]) is among the top-204.
__global__ void k_binary(const float* __restrict__ mask_w, float* __restrict__ bin) {
    __shared__ float s[H];
    int t = threadIdx.x;
    float sv = 1.0f / (1.0f + __expf(-mask_w[t]));
    s[t] = sv;
    __syncthreads();
    int cnt = 0;
    for (int j = 0; j < H; ++j) cnt += (s[j] > sv) ? 1 : 0;
    bin[t] = (cnt < KKEEP) ? 1.0f : 0.0f;
}

__global__ void k_maskout(const float* __restrict__ bin, float* __restrict__ mout) {
    int i = blockIdx.x * 256 + threadIdx.x;
    if (i < B * W * H) mout[i] = bin[i & (H - 1)];
}

// ---------------------------------------------------------------------------
// K/V projection -> bf16. k16: [b][n][d] row-major. vT16: [b][d][n].
__global__ void k_kv(const float* __restrict__ v, const float* __restrict__ Wk,
                     const float* __restrict__ Wv, ushort* __restrict__ k16,
                     ushort* __restrict__ vT16) {
    __shared__ float vrow[DCOND];
    int bn = blockIdx.x;              // b*NCOND + n
    int t  = threadIdx.x;             // output column e
    const float* vp = v + bn * DCOND;
    for (int i = t; i < DCOND; i += 256) vrow[i] = vp[i];
    __syncthreads();
    float ka = 0.f, va = 0.f;
    for (int d4 = 0; d4 < DCOND / 4; ++d4) {
        float4 vv = *(const float4*)(vrow + d4 * 4);
        const float* wk = Wk + (d4 * 4) * DATTN + t;
        const float* wv = Wv + (d4 * 4) * DATTN + t;
        ka += vv.x * wk[0];         va += vv.x * wv[0];
        ka += vv.y * wk[DATTN];     va += vv.y * wv[DATTN];
        ka += vv.z * wk[2 * DATTN]; va += vv.z * wv[2 * DATTN];
        ka += vv.w * wk[3 * DATTN]; va += vv.w * wv[3 * DATTN];
    }
    k16[bn * DATTN + t] = f2bf(ka);
    int b = bn >> 9, n = bn & 511;
    vT16[b * (DATTN * NCOND) + t * NCOND + n] = f2bf(va);
}

// Wq^T [d][h], Wo^T [h][d] in bf16.
__global__ void k_prep(const float* __restrict__ Wq, const float* __restrict__ Wo,
                       ushort* __restrict__ wqT, ushort* __restrict__ woT) {
    int i = blockIdx.x * 256 + threadIdx.x;
    if (i < 65536) {
        int d = i >> 8, h = i & 255;
        wqT[i] = f2bf(Wq[h * 256 + d]);
    } else {
        int j = i - 65536;
        int h = j >> 8, d = j & 255;
        woT[j] = f2bf(Wo[d * 256 + h]);
    }
}

// conv weights -> w9[p = ky*3+kx][co][ci] bf16 (K-major rows for MFMA B operand).
__global__ void k_w9(const float* __restrict__ cw, ushort* __restrict__ w9) {
    int i = blockIdx.x * 256 + threadIdx.x;
    if (i >= 9 * 128 * 256) return;
    int p  = i >> 15;
    int r  = i & 32767;
    int co = r >> 8;
    int ci = r & 255;
    w9[i] = f2bf(cw[(co * 256 + ci) * 9 + p]);
}

// ---------------------------------------------------------------------------
// Fused MFMA cross-attention (round-2 structure, bf16 output).
__launch_bounds__(256)
__global__ void k_attn(const float* __restrict__ x, const ushort* __restrict__ k16,
                       const ushort* __restrict__ vT16, const ushort* __restrict__ wqT,
                       const ushort* __restrict__ woT, const float* __restrict__ bo,
                       ushort* __restrict__ af16) {
    __shared__ __align__(16) char arena[50176];
    char* arenaB = arena + 32768;
    float* smax = (float*)(arena + 49152);
    float* ssum = (float*)(arena + 49664);

    const int t   = threadIdx.x;
    const int blk = blockIdx.x;
    const int b   = blk >> 11;
    const int ci  = (blk >> 4) & 127;
    const int w0  = (blk & 15) << 5;
    const int wid = t >> 6;
    const int lr  = t & 15;
    const int lg  = (t & 63) >> 4;

    // ---- Phase 1: load X tile -> Xs[w][h] bf16 (thread t = h)
    {
        const float* xp = x + (((size_t)b * C + ci) * H + t) * W + w0;
#pragma unroll
        for (int j4 = 0; j4 < 8; ++j4) {
            float4 v4 = *(const float4*)(xp + j4 * 4);
            int j = j4 * 4;
            *(ushort*)(arena + (j + 0) * 512 + ((2 * t) ^ (((j + 0) & 7) << 4))) = f2bf(v4.x);
            *(ushort*)(arena + (j + 1) * 512 + ((2 * t) ^ (((j + 1) & 7) << 4))) = f2bf(v4.y);
            *(ushort*)(arena + (j + 2) * 512 + ((2 * t) ^ (((j + 2) & 7) << 4))) = f2bf(v4.z);
            *(ushort*)(arena + (j + 3) * 512 + ((2 * t) ^ (((j + 3) & 7) << 4))) = f2bf(v4.w);
        }
    }
    __syncthreads();

    // ---- Phase 2: Q = Xs @ WqT  -> Qs (arenaB)
    {
        f32x4 qac[2][4];
#pragma unroll
        for (int mb = 0; mb < 2; ++mb)
#pragma unroll
            for (int nb = 0; nb < 4; ++nb) qac[mb][nb] = (f32x4){0.f, 0.f, 0.f, 0.f};
        for (int ks = 0; ks < 8; ++ks) {
            int kb = (ks * 64 + lg * 16) ^ ((lr & 7) << 4);
            bf16x8 a0 = *(const bf16x8*)(arena + lr * 512 + kb);
            bf16x8 a1 = *(const bf16x8*)(arena + (16 + lr) * 512 + kb);
            const ushort* wq0 = wqT + ks * 32 + lg * 8;
#pragma unroll
            for (int nb = 0; nb < 4; ++nb) {
                int d = wid * 64 + nb * 16 + lr;
                bf16x8 bf = *(const bf16x8*)(wq0 + d * 256);
                qac[0][nb] = __builtin_amdgcn_mfma_f32_16x16x32_bf16(a0, bf, qac[0][nb], 0, 0, 0);
                qac[1][nb] = __builtin_amdgcn_mfma_f32_16x16x32_bf16(a1, bf, qac[1][nb], 0, 0, 0);
            }
        }
#pragma unroll
        for (int mb = 0; mb < 2; ++mb)
#pragma unroll
            for (int nb = 0; nb < 4; ++nb)
#pragma unroll
                for (int r = 0; r < 4; ++r) {
                    int m = mb * 16 + lg * 4 + r;
                    int d = wid * 64 + nb * 16 + lr;
                    *(ushort*)(arenaB + m * 512 + ((2 * d) ^ ((m & 7) << 4))) = f2bf(qac[mb][nb][r]);
                }
    }
    __syncthreads();

    // ---- Phase 3: S = Qs @ K^T (wave n-slice of 128), softmax stats, P -> arenaA
    float rinv[2][4];
    {
        f32x4 sac[2][8];
#pragma unroll
        for (int mb = 0; mb < 2; ++mb)
#pragma unroll
            for (int nb = 0; nb < 8; ++nb) sac[mb][nb] = (f32x4){0.f, 0.f, 0.f, 0.f};
        const ushort* kb16 = k16 + (size_t)b * (NCOND * DATTN);
        for (int ks = 0; ks < 8; ++ks) {
            int kb = (ks * 64 + lg * 16) ^ ((lr & 7) << 4);
            bf16x8 a0 = *(const bf16x8*)(arenaB + lr * 512 + kb);
            bf16x8 a1 = *(const bf16x8*)(arenaB + (16 + lr) * 512 + kb);
            const ushort* kp = kb16 + ks * 32 + lg * 8;
#pragma unroll
            for (int nb = 0; nb < 8; ++nb) {
                int n = wid * 128 + nb * 16 + lr;
                bf16x8 bf = *(const bf16x8*)(kp + n * 256);
                sac[0][nb] = __builtin_amdgcn_mfma_f32_16x16x32_bf16(a0, bf, sac[0][nb], 0, 0, 0);
                sac[1][nb] = __builtin_amdgcn_mfma_f32_16x16x32_bf16(a1, bf, sac[1][nb], 0, 0, 0);
            }
        }
        float pmax[2][4];
#pragma unroll
        for (int mb = 0; mb < 2; ++mb)
#pragma unroll
            for (int r = 0; r < 4; ++r) {
                float m = sac[mb][0][r];
#pragma unroll
                for (int nb = 1; nb < 8; ++nb) m = fmaxf(m, sac[mb][nb][r]);
#pragma unroll
                for (int o = 8; o >= 1; o >>= 1) m = fmaxf(m, __shfl_xor(m, o));
                pmax[mb][r] = m;
            }
        if (lr == 0) {
#pragma unroll
            for (int mb = 0; mb < 2; ++mb)
#pragma unroll
                for (int r = 0; r < 4; ++r)
                    smax[(mb * 16 + lg * 4 + r) * 4 + wid] = pmax[mb][r];
        }
        __syncthreads();
        float psum[2][4];
#pragma unroll
        for (int mb = 0; mb < 2; ++mb)
#pragma unroll
            for (int r = 0; r < 4; ++r) {
                int m = mb * 16 + lg * 4 + r;
                float g = fmaxf(fmaxf(smax[m * 4], smax[m * 4 + 1]),
                                fmaxf(smax[m * 4 + 2], smax[m * 4 + 3]));
                float s = 0.f;
#pragma unroll
                for (int nb = 0; nb < 8; ++nb) {
                    float e = __expf(sac[mb][nb][r] - g);
                    s += e;
                    int n = wid * 128 + nb * 16 + lr;
                    *(ushort*)(arena + m * 1024 + ((2 * n) ^ ((m & 7) << 4))) = f2bf(e);
                }
#pragma unroll
                for (int o = 8; o >= 1; o >>= 1) s += __shfl_xor(s, o);
                psum[mb][r] = s;
            }
        if (lr == 0) {
#pragma unroll
            for (int mb = 0; mb < 2; ++mb)
#pragma unroll
                for (int r = 0; r < 4; ++r)
                    ssum[(mb * 16 + lg * 4 + r) * 4 + wid] = psum[mb][r];
        }
        __syncthreads();
#pragma unroll
        for (int mb = 0; mb < 2; ++mb)
#pragma unroll
            for (int r = 0; r < 4; ++r) {
                int m = mb * 16 + lg * 4 + r;
                rinv[mb][r] = 1.0f / (ssum[m * 4] + ssum[m * 4 + 1] + ssum[m * 4 + 2] + ssum[m * 4 + 3]);
            }
    }

    // ---- Phase 4: O = P @ V (wave d-slice of 64), scale by rinv -> Os (arenaB)
    {
        f32x4 oac[2][4];
#pragma unroll
        for (int mb = 0; mb < 2; ++mb)
#pragma unroll
            for (int nb = 0; nb < 4; ++nb) oac[mb][nb] = (f32x4){0.f, 0.f, 0.f, 0.f};
        const ushort* vb16 = vT16 + (size_t)b * (NCOND * DATTN);
        for (int ks = 0; ks < 16; ++ks) {
            int kb = (ks * 64 + lg * 16) ^ ((lr & 7) << 4);
            bf16x8 a0 = *(const bf16x8*)(arena + lr * 1024 + kb);
            bf16x8 a1 = *(const bf16x8*)(arena + (16 + lr) * 1024 + kb);
            const ushort* vp = vb16 + ks * 32 + lg * 8;
#pragma unroll
            for (int nb = 0; nb < 4; ++nb) {
                int d = wid * 64 + nb * 16 + lr;
                bf16x8 bf = *(const bf16x8*)(vp + d * 512);
                oac[0][nb] = __builtin_amdgcn_mfma_f32_16x16x32_bf16(a0, bf, oac[0][nb], 0, 0, 0);
                oac[1][nb] = __builtin_amdgcn_mfma_f32_16x16x32_bf16(a1, bf, oac[1][nb], 0, 0, 0);
            }
        }
        __syncthreads();
#pragma unroll
        for (int mb = 0; mb < 2; ++mb)
#pragma unroll
            for (int nb = 0; nb < 4; ++nb)
#pragma unroll
                for (int r = 0; r < 4; ++r) {
                    int m = mb * 16 + lg * 4 + r;
                    int d = wid * 64 + nb * 16 + lr;
                    *(ushort*)(arenaB + m * 512 + ((2 * d) ^ ((m & 7) << 4))) =
                        f2bf(oac[mb][nb][r] * rinv[mb][r]);
                }
    }
    __syncthreads();

    // ---- Phase 5: AF = Os @ WoT + bo -> af16 (bf16 NCHW)
    {
        f32x4 aac[2][4];
#pragma unroll
        for (int mb = 0; mb < 2; ++mb)
#pragma unroll
            for (int nb = 0; nb < 4; ++nb) aac[mb][nb] = (f32x4){0.f, 0.f, 0.f, 0.f};
        for (int ks = 0; ks < 8; ++ks) {
            int kb = (ks * 64 + lg * 16) ^ ((lr & 7) << 4);
            bf16x8 a0 = *(const bf16x8*)(arenaB + lr * 512 + kb);
            bf16x8 a1 = *(const bf16x8*)(arenaB + (16 + lr) * 512 + kb);
            const ushort* wo0 = woT + ks * 32 + lg * 8;
#pragma unroll
            for (int nb = 0; nb < 4; ++nb) {
                int h = wid * 64 + nb * 16 + lr;
                bf16x8 bf = *(const bf16x8*)(wo0 + h * 256);
                aac[0][nb] = __builtin_amdgcn_mfma_f32_16x16x32_bf16(a0, bf, aac[0][nb], 0, 0, 0);
                aac[1][nb] = __builtin_amdgcn_mfma_f32_16x16x32_bf16(a1, bf, aac[1][nb], 0, 0, 0);
            }
        }
        size_t afbase = ((size_t)b * C + ci) * H * W;
#pragma unroll
        for (int nb = 0; nb < 4; ++nb) {
            int h = wid * 64 + nb * 16 + lr;
            float bias = bo[h];
            ushort* op = af16 + afbase + (size_t)h * W + w0;
#pragma unroll
            for (int mb = 0; mb < 2; ++mb) {
                ushort4 u;
                u.x = f2bf(aac[mb][nb][0] + bias);
                u.y = f2bf(aac[mb][nb][1] + bias);
                u.z = f2bf(aac[mb][nb][2] + bias);
                u.w = f2bf(aac[mb][nb][3] + bias);
                *(ushort4*)(op + mb * 16 + lg * 4) = u;
            }
        }
    }
}

// ---------------------------------------------------------------------------
// Build NHWC bf16 cat: catn[b][y][x][cc] = cc<128 ? x*bin : af.  (round-3 proven)
__launch_bounds__(256)
__global__ void k_cat(const float* __restrict__ x, const ushort* __restrict__ af16,
                      const float* __restrict__ bin, ushort* __restrict__ catn) {
    __shared__ __align__(16) char st[32768];
    const int t   = threadIdx.x;
    const int blk = blockIdx.x;
    const int xt  = blk & 7;
    const int y   = (blk >> 3) & 255;
    const int b   = blk >> 11;
    const int x0  = xt * 64;
    const float bw = bin[y];

    for (int i = t; i < 2048; i += 256) {
        int cc = i >> 4, c4 = i & 15;
        float4 v = *(const float4*)(x + (((size_t)b * C + cc) * H + y) * W + x0 + c4 * 4);
#pragma unroll
        for (int j = 0; j < 4; ++j) {
            int px = c4 * 4 + j;
            float f = (j == 0 ? v.x : j == 1 ? v.y : j == 2 ? v.z : v.w) * bw;
            *(ushort*)(st + px * 512 + ((2 * cc) ^ ((px & 7) << 4))) = f2bf(f);
        }
    }
    for (int i = t; i < 1024; i += 256) {
        int cc = i >> 3, c8 = i & 7;
        U8 v;
        v.v = *(const bf16x8*)(af16 + (((size_t)b * C + cc) * H + y) * W + x0 + c8 * 8);
#pragma unroll
        for (int j = 0; j < 8; ++j) {
            int px = c8 * 8 + j;
            *(ushort*)(st + px * 512 + ((2 * (128 + cc)) ^ ((px & 7) << 4))) = v.u[j];
        }
    }
    __syncthreads();
    for (int i = t; i < 2048; i += 256) {
        int px = i >> 5, c16 = i & 31;
        bf16x8 v = *(const bf16x8*)(st + px * 512 + ((c16 * 16) ^ ((px & 7) << 4)));
        *(bf16x8*)(catn + (((size_t)b * H + y) * W + x0 + px) * 256 + c16 * 8) = v;
    }
}

// ---------------------------------------------------------------------------
// MFMA conv3x3, GEMM-shaped. Block = (b, 4-row y-strip, 64-px x-tile), 128 co.
// 8 waves = 4 rows (wm) x 2 co-halves (wn); wave tile = 64 px x 64 co.
// LDS: [6 rows][66 px][128-cc chunk] bf16 (XOR-swizzled), 2 chunks sequential.
// Per (dy,dx): 16 batched weight frags (L2) then 4 ks x (4 ds_read + 16 MFMA).
__launch_bounds__(512, 2)
__global__ void k_convg(const ushort* __restrict__ catn, const ushort* __restrict__ w9,
                        const float* __restrict__ conv_b, float* __restrict__ out,
                        float* __restrict__ pb) {
    __shared__ __align__(16) char st[101376];    // 6 * 66 * 256 B
    __shared__ float pst[4][64];
    const int t   = threadIdx.x;
    const int blk = blockIdx.x;
    const int xt  = blk & 7;
    const int yq  = (blk >> 3) & 63;
    const int b   = blk >> 9;
    const int x0  = xt * 64;
    const int y0  = yq * 4;
    const int wid = t >> 6;
    const int wm  = wid >> 1;        // output row within quad (0..3)
    const int wn  = wid & 1;         // co half (0..1)
    const int lr  = t & 15;
    const int lg  = (t & 63) >> 4;

    f32x4 acc[4][4];
#pragma unroll
    for (int mb = 0; mb < 4; ++mb)
#pragma unroll
        for (int nb = 0; nb < 4; ++nb) acc[mb][nb] = (f32x4){0.f, 0.f, 0.f, 0.f};

    for (int c = 0; c < 2; ++c) {                // 128-cc chunk
        __syncthreads();
        // ---- stage: 6 rows x 66 px x 128 cc, all b128, swizzled
        for (int e = t; e < 6336; e += 512) {
            int r   = e / 1056;
            int rem = e - r * 1056;
            int px  = rem >> 4;
            int cg  = rem & 15;
            int iy  = y0 - 1 + r;
            int gx  = x0 - 1 + px;
            bf16x8 val = {0, 0, 0, 0, 0, 0, 0, 0};
            if ((unsigned)iy < (unsigned)H && (unsigned)gx < (unsigned)W)
                val = *(const bf16x8*)(catn + (((size_t)b * H + iy) * W + gx) * 256 + c * 128 + cg * 8);
            *(bf16x8*)(st + r * 16896 + px * 256 + ((cg * 16) ^ ((px & 7) << 4))) = val;
        }
        __syncthreads();
#pragma unroll
        for (int dy = 0; dy < 3; ++dy) {
            const char* arow = st + (wm + dy) * 16896;
#pragma unroll
            for (int dx = 0; dx < 3; ++dx) {
                const ushort* wp = w9 + (size_t)(dy * 3 + dx) * 32768
                                 + (size_t)(wn * 64 + lr) * 256 + c * 128 + lg * 8;
                bf16x8 bfr[4][4];                // [nb][ks], 64 VGPR, one L2 latency
#pragma unroll
                for (int nb = 0; nb < 4; ++nb)
#pragma unroll
                    for (int ks = 0; ks < 4; ++ks)
                        bfr[nb][ks] = *(const bf16x8*)(wp + nb * 16 * 256 + ks * 32);
#pragma unroll
                for (int ks = 0; ks < 4; ++ks) {
                    bf16x8 afr[4];
#pragma unroll
                    for (int mb = 0; mb < 4; ++mb) {
                        int px = mb * 16 + lr + dx;
                        afr[mb] = *(const bf16x8*)(arow + px * 256 + ((ks * 64 + lg * 16) ^ ((px & 7) << 4)));
                    }
#pragma unroll
                    for (int nb = 0; nb < 4; ++nb)
#pragma unroll
                        for (int mb = 0; mb < 4; ++mb)
                            acc[mb][nb] = __builtin_amdgcn_mfma_f32_16x16x32_bf16(afr[mb], bfr[nb][ks], acc[mb][nb], 0, 0, 0);
                }
            }
        }
    }

    // ---- epilogue: bias, f32 NCHW store, per-group GN partials
#pragma unroll
    for (int nb = 0; nb < 4; ++nb) {
        int co = wn * 64 + nb * 16 + lr;
        float bias = conv_b[co];
        float s = 0.f, ss = 0.f;
        float* op = out + (((size_t)b * C + co) * H + (y0 + wm)) * W + x0;
#pragma unroll
        for (int mb = 0; mb < 4; ++mb) {
            float4 o = make_float4(acc[mb][nb][0] + bias, acc[mb][nb][1] + bias,
                                   acc[mb][nb][2] + bias, acc[mb][nb][3] + bias);
            s  += (o.x + o.y) + (o.z + o.w);
            ss += (o.x * o.x + o.y * o.y) + (o.z * o.z + o.w * o.w);
            *(float4*)(op + mb * 16 + lg * 4) = o;
        }
        s += __shfl_xor(s, 1);  ss += __shfl_xor(ss, 1);    // co within group of 4
        s += __shfl_xor(s, 2);  ss += __shfl_xor(ss, 2);
        s += __shfl_xor(s, 16); ss += __shfl_xor(ss, 16);   // px quarters (lg)
        s += __shfl_xor(s, 32); ss += __shfl_xor(ss, 32);
        if (lg == 0 && (lr & 3) == 0) {
            int g = co >> 2;
            pst[wm][g * 2]     = s;
            pst[wm][g * 2 + 1] = ss;
        }
    }
    __syncthreads();
    if (t < 64)
        pb[(size_t)blk * 64 + t] = pst[0][t] + pst[1][t] + pst[2][t] + pst[3][t];
}

// ---------------------------------------------------------------------------
// Reduce per-block GN partials -> mean/rstd per (b, group). 64 blocks.
__global__ void k_stats2(const float* __restrict__ pb, float* __restrict__ st2) {
    __shared__ float red[512];
    int blk = blockIdx.x;            // b*32 + g
    int b = blk >> 5, g = blk & 31;
    int t = threadIdx.x;
    float s = 0.f, ss = 0.f;
    for (int j = t; j < 512; j += 256) {         // 512 conv blocks per batch
        const float* p = pb + ((size_t)(b * 512 + j)) * 64 + g * 2;
        s += p[0]; ss += p[1];
    }
    red[t * 2] = s; red[t * 2 + 1] = ss;
    __syncthreads();
    for (int o = 128; o >= 1; o >>= 1) {
        if (t < o) {
            red[t * 2]     += red[(t + o) * 2];
            red[t * 2 + 1] += red[(t + o) * 2 + 1];
        }
        __syncthreads();
    }
    if (t == 0) {
        const float inv = 1.0f / 524288.0f;      // 4 ch * 256 * 512
        float mean = red[0] * inv;
        float var  = red[1] * inv - mean * mean;
        st2[blk * 2]     = mean;
        st2[blk * 2 + 1] = rsqrtf(var + 1e-6f);
    }
}

// GroupNorm normalize + affine + SiLU, in place on d_out.
__global__ void k_norm(const float* __restrict__ st2, const float* __restrict__ gamma,
                       const float* __restrict__ beta, float* __restrict__ out) {
    const int N4 = B * C * H * W / 4;
    int stride = gridDim.x * 256;
    for (int i4 = blockIdx.x * 256 + threadIdx.x; i4 < N4; i4 += stride) {
        int i = i4 * 4;
        int c = (i >> 17) & 127;
        int b = i >> 24;
        int g = c >> 2;
        float mean = st2[(b * 32 + g) * 2];
        float rstd = st2[(b * 32 + g) * 2 + 1];
        float ga = gamma[c], be = beta[c];
        float4 v = *(float4*)(out + i);
        float n0 = (v.x - mean) * rstd * ga + be;
        float n1 = (v.y - mean) * rstd * ga + be;
        float n2 = (v.z - mean) * rstd * ga + be;
        float n3 = (v.w - mean) * rstd * ga + be;
        v.x = n0 / (1.0f + __expf(-n0));
        v.y = n1 / (1.0f + __expf(-n1));
        v.z = n2 / (1.0f + __expf(-n2));
        v.w = n3 / (1.0f + __expf(-n3));
        *(float4*)(out + i) = v;
    }
}

// ---------------------------------------------------------------------------
extern "C" void kernel_launch(void* const* d_in, const int* in_sizes, int n_in,
                              void* d_out, int out_size, void* d_ws, size_t ws_size,
                              hipStream_t stream) {
    const float* x      = (const float*)d_in[0];
    const float* v      = (const float*)d_in[1];
    const float* Wq     = (const float*)d_in[2];
    const float* Wk     = (const float*)d_in[3];
    const float* Wv     = (const float*)d_in[4];
    const float* Wo     = (const float*)d_in[5];
    const float* bo     = (const float*)d_in[6];
    const float* mask_w = (const float*)d_in[7];
    const float* conv_w = (const float*)d_in[8];
    const float* conv_b = (const float*)d_in[9];
    const float* gng    = (const float*)d_in[10];
    const float* gnb    = (const float*)d_in[11];

    float* out  = (float*)d_out;
    float* mout = out + B * C * H * W;
    // d_out's 128 MB out-region is dead until k_convg writes it -> first 64 MB
    // holds the bf16 attn feature (consumed by k_cat strictly before k_convg).
    ushort* af16 = (ushort*)d_out;

    char*  wsb  = (char*)d_ws;
    ushort* catn = (ushort*)(wsb + WS_CATN);
    ushort* k16  = (ushort*)(wsb + WS_K16);
    ushort* vT16 = (ushort*)(wsb + WS_VT16);
    ushort* wqT  = (ushort*)(wsb + WS_WQT);
    ushort* woT  = (ushort*)(wsb + WS_WOT);
    ushort* w9   = (ushort*)(wsb + WS_W9);
    float* bin   = (float*)(wsb + WS_BIN);
    float* st2   = (float*)(wsb + WS_ST2);
    // pb (1024 blocks x 64 f32 = 256 KB) reuses the wqT/woT region (dead after k_attn).
    float* pb    = (float*)(wsb + WS_WQT);

    k_binary <<<1,    256, 0, stream>>>(mask_w, bin);
    k_maskout<<<1024, 256, 0, stream>>>(bin, mout);
    k_kv     <<<B * NCOND, 256, 0, stream>>>(v, Wk, Wv, k16, vT16);
    k_prep   <<<512,  256, 0, stream>>>(Wq, Wo, wqT, woT);
    k_w9     <<<1152, 256, 0, stream>>>(conv_w, w9);
    k_attn   <<<4096, 256, 0, stream>>>(x, k16, vT16, wqT, woT, bo, af16);
    k_cat    <<<4096, 256, 0, stream>>>(x, af16, bin, catn);
    k_convg  <<<1024, 512, 0, stream>>>(catn, w9, conv_b, out, pb);
    k_stats2 <<<64,   256, 0, stream>>>(pb, st2);
    k_norm   <<<2048, 256, 0, stream>>>(st2, gng, gnb, out);
}

// Round 6
// 847.262 us; speedup vs baseline: 7.1191x; 1.0896x over previous
//
#include <hip/hip_runtime.h>
#include <math.h>

// Problem constants (from reference setup_inputs)
#define B      2
#define C      128     // channels
#define H      256     // d_model == image height
#define W      512     // image width
#define NCOND  512
#define DCOND  512
#define DATTN  256
#define KKEEP  204     // int(256 * (1 - 0.2))

// Workspace layout (byte offsets). Total ~136.1 MB (proven footprint).
#define WS_CATN   0ull          // bf16 NHWC cat [B][H][W][256]     134217728 B
#define WS_KQ     134217728ull  // bf16 kq  [B][n=512][h=256]       524288 B
#define WS_VOT    134742016ull  // bf16 voT [B][h=256][n=512]       524288 B
#define WS_PB     135266304ull  // f32 GN partials [1024][64]       262144 B
#define WS_W9     135528448ull  // bf16 w9 [9][co=128][ci=256]      589824 B
#define WS_BIN    136118272ull  // f32 binary[256]                  1024 B
#define WS_ST2    136119296ull  // f32 final stats [B][32][2]       512 B

typedef __attribute__((ext_vector_type(8))) short bf16x8;
typedef __attribute__((ext_vector_type(4))) float f32x4;

union U8 { bf16x8 v; ushort u[8]; };

__device__ inline ushort f2bf(float f) {
    union { float f; unsigned u; } v; v.f = f;
    unsigned r = v.u + 0x7fffu + ((v.u >> 16) & 1u);   // RNE
    return (ushort)(r >> 16);
}

// ---------------------------------------------------------------------------
// Learned mask: binary[h] = 1 iff sigmoid(mask_w[h]) is among the top-204.
__global__ void k_binary(const float* __restrict__ mask_w, float* __restrict__ bin) {
    __shared__ float s[H];
    int t = threadIdx.x;
    float sv = 1.0f / (1.0f + __expf(-mask_w[t]));
    s[t] = sv;
    __syncthreads();
    int cnt = 0;
    for (int j = 0; j < H; ++j) cnt += (s[j] > sv) ? 1 : 0;
    bin[t] = (cnt < KKEEP) ? 1.0f : 0.0f;
}

__global__ void k_maskout(const float* __restrict__ bin, float* __restrict__ mout) {
    int i = blockIdx.x * 256 + threadIdx.x;
    if (i < B * W * H) mout[i] = bin[i & (H - 1)];
}

// ---------------------------------------------------------------------------
// K/V projection + weight folding (associativity):
//   kq[b][n][h]  = sum_d (v.Wk)[n,d] * Wq[h,d]   (S = X @ kq^T)
//   voT[b][h][n] = sum_d (v.Wv)[n,d] * Wo[d,h]   (out = P @ voT^T)
// All inner math f32; single bf16 rounding at the end.
__launch_bounds__(256)
__global__ void k_kv(const float* __restrict__ v, const float* __restrict__ Wk,
                     const float* __restrict__ Wv, const float* __restrict__ Wq,
                     const float* __restrict__ Wo, ushort* __restrict__ kq16,
                     ushort* __restrict__ voT16) {
    __shared__ float vrow[DCOND];
    __shared__ float kld[DATTN];
    __shared__ float vld[DATTN];
    int bn = blockIdx.x;              // b*NCOND + n
    int t  = threadIdx.x;
    const float* vp = v + (size_t)bn * DCOND;
    for (int i = t; i < DCOND; i += 256) vrow[i] = vp[i];
    __syncthreads();
    float ka = 0.f, va = 0.f;
    for (int d4 = 0; d4 < DCOND / 4; ++d4) {
        float4 vv = *(const float4*)(vrow + d4 * 4);
        const float* wk = Wk + (d4 * 4) * DATTN + t;
        const float* wv = Wv + (d4 * 4) * DATTN + t;
        ka += vv.x * wk[0];         va += vv.x * wv[0];
        ka += vv.y * wk[DATTN];     va += vv.y * wv[DATTN];
        ka += vv.z * wk[2 * DATTN]; va += vv.z * wv[2 * DATTN];
        ka += vv.w * wk[3 * DATTN]; va += vv.w * wv[3 * DATTN];
    }
    kld[t] = ka; vld[t] = va;
    __syncthreads();
    // kq[n][h=t] = sum_d kld[d] * Wq[t][d]   (per-thread Wq row, L2-resident)
    float kq = 0.f;
    const float4* wqr = (const float4*)(Wq + (size_t)t * DATTN);
#pragma unroll 8
    for (int d4 = 0; d4 < DATTN / 4; ++d4) {
        float4 w = wqr[d4];
        kq += kld[d4 * 4] * w.x + kld[d4 * 4 + 1] * w.y
            + kld[d4 * 4 + 2] * w.z + kld[d4 * 4 + 3] * w.w;
    }
    // vo[n][h=t] = sum_d vld[d] * Wo[d][t]   (coalesced per d)
    float vo = 0.f;
#pragma unroll 8
    for (int d = 0; d < DATTN; ++d) vo += vld[d] * Wo[(size_t)d * 256 + t];
    kq16[(size_t)bn * 256 + t] = f2bf(kq);
    int b = bn >> 9, n = bn & 511;
    voT16[((size_t)b * 256 + t) * 512 + n] = f2bf(vo);
}

// conv weights -> w9[p = ky*3+kx][co][ci] bf16 (K-major rows for MFMA B operand).
__global__ void k_w9(const float* __restrict__ cw, ushort* __restrict__ w9) {
    int i = blockIdx.x * 256 + threadIdx.x;
    if (i >= 9 * 128 * 256) return;
    int p  = i >> 15;
    int r  = i & 32767;
    int co = r >> 8;
    int ci = r & 255;
    w9[i] = f2bf(cw[(co * 256 + ci) * 9 + p]);
}

// ---------------------------------------------------------------------------
// Fused MFMA cross-attention, 2-GEMM form. Block = 32 rows (b, ci, w0..w0+31).
// Phase 1: X -> LDS.  Phase 2: S = Xs @ kq^T + softmax -> P (overwrites Xs).
// Phase 3: out = (P @ voT) * rinv + bo -> af16.   LDS 33.8 KB -> 4 blocks/CU.
__launch_bounds__(256)
__global__ void k_attn(const float* __restrict__ x, const ushort* __restrict__ kq16,
                       const ushort* __restrict__ voT16, const float* __restrict__ bo,
                       ushort* __restrict__ af16) {
    __shared__ __align__(16) char arena[33792];
    float* smax = (float*)(arena + 32768);
    float* ssum = (float*)(arena + 33280);

    const int t   = threadIdx.x;
    const int blk = blockIdx.x;
    const int b   = blk >> 11;
    const int ci  = (blk >> 4) & 127;
    const int w0  = (blk & 15) << 5;
    const int wid = t >> 6;
    const int lr  = t & 15;
    const int lg  = (t & 63) >> 4;

    // ---- Phase 1: load X tile -> Xs[w][h] bf16 (thread t = h)
    {
        const float* xp = x + (((size_t)b * C + ci) * H + t) * W + w0;
#pragma unroll
        for (int j4 = 0; j4 < 8; ++j4) {
            float4 v4 = *(const float4*)(xp + j4 * 4);
            int j = j4 * 4;
            *(ushort*)(arena + (j + 0) * 512 + ((2 * t) ^ (((j + 0) & 7) << 4))) = f2bf(v4.x);
            *(ushort*)(arena + (j + 1) * 512 + ((2 * t) ^ (((j + 1) & 7) << 4))) = f2bf(v4.y);
            *(ushort*)(arena + (j + 2) * 512 + ((2 * t) ^ (((j + 2) & 7) << 4))) = f2bf(v4.z);
            *(ushort*)(arena + (j + 3) * 512 + ((2 * t) ^ (((j + 3) & 7) << 4))) = f2bf(v4.w);
        }
    }
    __syncthreads();

    // ---- Phase 2: S = Xs @ kq^T (wave n-slice of 128), softmax, P -> arena
    float rinv[2][4];
    {
        f32x4 sac[2][8];
#pragma unroll
        for (int mb = 0; mb < 2; ++mb)
#pragma unroll
            for (int nb = 0; nb < 8; ++nb) sac[mb][nb] = (f32x4){0.f, 0.f, 0.f, 0.f};
        const ushort* kqb = kq16 + (size_t)b * (NCOND * DATTN);
        for (int ks = 0; ks < 8; ++ks) {
            int kb = (ks * 64 + lg * 16) ^ ((lr & 7) << 4);
            bf16x8 a0 = *(const bf16x8*)(arena + lr * 512 + kb);
            bf16x8 a1 = *(const bf16x8*)(arena + (16 + lr) * 512 + kb);
            const ushort* kp = kqb + ks * 32 + lg * 8;
#pragma unroll
            for (int nb = 0; nb < 8; ++nb) {
                int n = wid * 128 + nb * 16 + lr;
                bf16x8 bf = *(const bf16x8*)(kp + n * 256);
                sac[0][nb] = __builtin_amdgcn_mfma_f32_16x16x32_bf16(a0, bf, sac[0][nb], 0, 0, 0);
                sac[1][nb] = __builtin_amdgcn_mfma_f32_16x16x32_bf16(a1, bf, sac[1][nb], 0, 0, 0);
            }
        }
        float pmax[2][4];
#pragma unroll
        for (int mb = 0; mb < 2; ++mb)
#pragma unroll
            for (int r = 0; r < 4; ++r) {
                float m = sac[mb][0][r];
#pragma unroll
                for (int nb = 1; nb < 8; ++nb) m = fmaxf(m, sac[mb][nb][r]);
#pragma unroll
                for (int o = 8; o >= 1; o >>= 1) m = fmaxf(m, __shfl_xor(m, o));
                pmax[mb][r] = m;
            }
        if (lr == 0) {
#pragma unroll
            for (int mb = 0; mb < 2; ++mb)
#pragma unroll
                for (int r = 0; r < 4; ++r)
                    smax[(mb * 16 + lg * 4 + r) * 4 + wid] = pmax[mb][r];
        }
        __syncthreads();    // also: all Xs reads complete before P overwrites
        float psum[2][4];
#pragma unroll
        for (int mb = 0; mb < 2; ++mb)
#pragma unroll
            for (int r = 0; r < 4; ++r) {
                int m = mb * 16 + lg * 4 + r;
                float g = fmaxf(fmaxf(smax[m * 4], smax[m * 4 + 1]),
                                fmaxf(smax[m * 4 + 2], smax[m * 4 + 3]));
                float s = 0.f;
#pragma unroll
                for (int nb = 0; nb < 8; ++nb) {
                    float e = __expf(sac[mb][nb][r] - g);
                    s += e;
                    int n = wid * 128 + nb * 16 + lr;
                    *(ushort*)(arena + m * 1024 + ((2 * n) ^ ((m & 7) << 4))) = f2bf(e);
                }
#pragma unroll
                for (int o = 8; o >= 1; o >>= 1) s += __shfl_xor(s, o);
                psum[mb][r] = s;
            }
        if (lr == 0) {
#pragma unroll
            for (int mb = 0; mb < 2; ++mb)
#pragma unroll
                for (int r = 0; r < 4; ++r)
                    ssum[(mb * 16 + lg * 4 + r) * 4 + wid] = psum[mb][r];
        }
        __syncthreads();
#pragma unroll
        for (int mb = 0; mb < 2; ++mb)
#pragma unroll
            for (int r = 0; r < 4; ++r) {
                int m = mb * 16 + lg * 4 + r;
                rinv[mb][r] = 1.0f / (ssum[m * 4] + ssum[m * 4 + 1] + ssum[m * 4 + 2] + ssum[m * 4 + 3]);
            }
    }

    // ---- Phase 3: out = (P @ voT) * rinv + bo -> af16 (bf16 NCHW)
    {
        f32x4 oac[2][4];
#pragma unroll
        for (int mb = 0; mb < 2; ++mb)
#pragma unroll
            for (int nb = 0; nb < 4; ++nb) oac[mb][nb] = (f32x4){0.f, 0.f, 0.f, 0.f};
        const ushort* vb = voT16 + (size_t)b * (DATTN * NCOND);
        for (int ks = 0; ks < 16; ++ks) {
            int kb = (ks * 64 + lg * 16) ^ ((lr & 7) << 4);
            bf16x8 a0 = *(const bf16x8*)(arena + lr * 1024 + kb);
            bf16x8 a1 = *(const bf16x8*)(arena + (16 + lr) * 1024 + kb);
            const ushort* vp = vb + ks * 32 + lg * 8;
#pragma unroll
            for (int nb = 0; nb < 4; ++nb) {
                int d = wid * 64 + nb * 16 + lr;
                bf16x8 bf = *(const bf16x8*)(vp + d * 512);
                oac[0][nb] = __builtin_amdgcn_mfma_f32_16x16x32_bf16(a0, bf, oac[0][nb], 0, 0, 0);
                oac[1][nb] = __builtin_amdgcn_mfma_f32_16x16x32_bf16(a1, bf, oac[1][nb], 0, 0, 0);
            }
        }
        size_t afbase = ((size_t)b * C + ci) * H * W;
#pragma unroll
        for (int nb = 0; nb < 4; ++nb) {
            int h = wid * 64 + nb * 16 + lr;
            float bias = bo[h];
            ushort* op = af16 + afbase + (size_t)h * W + w0;
#pragma unroll
            for (int mb = 0; mb < 2; ++mb) {
                ushort4 u;
                u.x = f2bf(oac[mb][nb][0] * rinv[mb][0] + bias);
                u.y = f2bf(oac[mb][nb][1] * rinv[mb][1] + bias);
                u.z = f2bf(oac[mb][nb][2] * rinv[mb][2] + bias);
                u.w = f2bf(oac[mb][nb][3] * rinv[mb][3] + bias);
                *(ushort4*)(op + mb * 16 + lg * 4) = u;
            }
        }
    }
}

// ---------------------------------------------------------------------------
// Build NHWC bf16 cat: catn[b][y][x][cc] = cc<128 ? x*bin : af.  (round-3 proven)
__launch_bounds__(256)
__global__ void k_cat(const float* __restrict__ x, const ushort* __restrict__ af16,
                      const float* __restrict__ bin, ushort* __restrict__ catn) {
    __shared__ __align__(16) char st[32768];
    const int t   = threadIdx.x;
    const int blk = blockIdx.x;
    const int xt  = blk & 7;
    const int y   = (blk >> 3) & 255;
    const int b   = blk >> 11;
    const int x0  = xt * 64;
    const float bw = bin[y];

    for (int i = t; i < 2048; i += 256) {
        int cc = i >> 4, c4 = i & 15;
        float4 v = *(const float4*)(x + (((size_t)b * C + cc) * H + y) * W + x0 + c4 * 4);
#pragma unroll
        for (int j = 0; j < 4; ++j) {
            int px = c4 * 4 + j;
            float f = (j == 0 ? v.x : j == 1 ? v.y : j == 2 ? v.z : v.w) * bw;
            *(ushort*)(st + px * 512 + ((2 * cc) ^ ((px & 7) << 4))) = f2bf(f);
        }
    }
    for (int i = t; i < 1024; i += 256) {
        int cc = i >> 3, c8 = i & 7;
        U8 v;
        v.v = *(const bf16x8*)(af16 + (((size_t)b * C + cc) * H + y) * W + x0 + c8 * 8);
#pragma unroll
        for (int j = 0; j < 8; ++j) {
            int px = c8 * 8 + j;
            *(ushort*)(st + px * 512 + ((2 * (128 + cc)) ^ ((px & 7) << 4))) = v.u[j];
        }
    }
    __syncthreads();
    for (int i = t; i < 2048; i += 256) {
        int px = i >> 5, c16 = i & 31;
        bf16x8 v = *(const bf16x8*)(st + px * 512 + ((c16 * 16) ^ ((px & 7) << 4)));
        *(bf16x8*)(catn + (((size_t)b * H + y) * W + x0 + px) * 256 + c16 * 8) = v;
    }
}

// ---------------------------------------------------------------------------
// MFMA conv3x3, GEMM-shaped (round-5 proven). Block = (b, 4-row strip, 64 px).
__launch_bounds__(512, 2)
__global__ void k_convg(const ushort* __restrict__ catn, const ushort* __restrict__ w9,
                        const float* __restrict__ conv_b, float* __restrict__ out,
                        float* __restrict__ pb) {
    __shared__ __align__(16) char st[101376];    // 6 * 66 * 256 B
    __shared__ float pst[4][64];
    const int t   = threadIdx.x;
    const int blk = blockIdx.x;
    const int xt  = blk & 7;
    const int yq  = (blk >> 3) & 63;
    const int b   = blk >> 9;
    const int x0  = xt * 64;
    const int y0  = yq * 4;
    const int wid = t >> 6;
    const int wm  = wid >> 1;
    const int wn  = wid & 1;
    const int lr  = t & 15;
    const int lg  = (t & 63) >> 4;

    f32x4 acc[4][4];
#pragma unroll
    for (int mb = 0; mb < 4; ++mb)
#pragma unroll
        for (int nb = 0; nb < 4; ++nb) acc[mb][nb] = (f32x4){0.f, 0.f, 0.f, 0.f};

    for (int c = 0; c < 2; ++c) {
        __syncthreads();
        for (int e = t; e < 6336; e += 512) {
            int r   = e / 1056;
            int rem = e - r * 1056;
            int px  = rem >> 4;
            int cg  = rem & 15;
            int iy  = y0 - 1 + r;
            int gx  = x0 - 1 + px;
            bf16x8 val = {0, 0, 0, 0, 0, 0, 0, 0};
            if ((unsigned)iy < (unsigned)H && (unsigned)gx < (unsigned)W)
                val = *(const bf16x8*)(catn + (((size_t)b * H + iy) * W + gx) * 256 + c * 128 + cg * 8);
            *(bf16x8*)(st + r * 16896 + px * 256 + ((cg * 16) ^ ((px & 7) << 4))) = val;
        }
        __syncthreads();
#pragma unroll
        for (int dy = 0; dy < 3; ++dy) {
            const char* arow = st + (wm + dy) * 16896;
#pragma unroll
            for (int dx = 0; dx < 3; ++dx) {
                const ushort* wp = w9 + (size_t)(dy * 3 + dx) * 32768
                                 + (size_t)(wn * 64 + lr) * 256 + c * 128 + lg * 8;
                bf16x8 bfr[4][4];
#pragma unroll
                for (int nb = 0; nb < 4; ++nb)
#pragma unroll
                    for (int ks = 0; ks < 4; ++ks)
                        bfr[nb][ks] = *(const bf16x8*)(wp + nb * 16 * 256 + ks * 32);
#pragma unroll
                for (int ks = 0; ks < 4; ++ks) {
                    bf16x8 afr[4];
#pragma unroll
                    for (int mb = 0; mb < 4; ++mb) {
                        int px = mb * 16 + lr + dx;
                        afr[mb] = *(const bf16x8*)(arow + px * 256 + ((ks * 64 + lg * 16) ^ ((px & 7) << 4)));
                    }
#pragma unroll
                    for (int nb = 0; nb < 4; ++nb)
#pragma unroll
                        for (int mb = 0; mb < 4; ++mb)
                            acc[mb][nb] = __builtin_amdgcn_mfma_f32_16x16x32_bf16(afr[mb], bfr[nb][ks], acc[mb][nb], 0, 0, 0);
                }
            }
        }
    }

#pragma unroll
    for (int nb = 0; nb < 4; ++nb) {
        int co = wn * 64 + nb * 16 + lr;
        float bias = conv_b[co];
        float s = 0.f, ss = 0.f;
        float* op = out + (((size_t)b * C + co) * H + (y0 + wm)) * W + x0;
#pragma unroll
        for (int mb = 0; mb < 4; ++mb) {
            float4 o = make_float4(acc[mb][nb][0] + bias, acc[mb][nb][1] + bias,
                                   acc[mb][nb][2] + bias, acc[mb][nb][3] + bias);
            s  += (o.x + o.y) + (o.z + o.w);
            ss += (o.x * o.x + o.y * o.y) + (o.z * o.z + o.w * o.w);
            *(float4*)(op + mb * 16 + lg * 4) = o;
        }
        s += __shfl_xor(s, 1);  ss += __shfl_xor(ss, 1);
        s += __shfl_xor(s, 2);  ss += __shfl_xor(ss, 2);
        s += __shfl_xor(s, 16); ss += __shfl_xor(ss, 16);
        s += __shfl_xor(s, 32); ss += __shfl_xor(ss, 32);
        if (lg == 0 && (lr & 3) == 0) {
            int g = co >> 2;
            pst[wm][g * 2]     = s;
            pst[wm][g * 2 + 1] = ss;
        }
    }
    __syncthreads();
    if (t < 64)
        pb[(size_t)blk * 64 + t] = pst[0][t] + pst[1][t] + pst[2][t] + pst[3][t];
}

// ---------------------------------------------------------------------------
__global__ void k_stats2(const float* __restrict__ pb, float* __restrict__ st2) {
    __shared__ float red[512];
    int blk = blockIdx.x;            // b*32 + g
    int b = blk >> 5, g = blk & 31;
    int t = threadIdx.x;
    float s = 0.f, ss = 0.f;
    for (int j = t; j < 512; j += 256) {
        const float* p = pb + ((size_t)(b * 512 + j)) * 64 + g * 2;
        s += p[0]; ss += p[1];
    }
    red[t * 2] = s; red[t * 2 + 1] = ss;
    __syncthreads();
    for (int o = 128; o >= 1; o >>= 1) {
        if (t < o) {
            red[t * 2]     += red[(t + o) * 2];
            red[t * 2 + 1] += red[(t + o) * 2 + 1];
        }
        __syncthreads();
    }
    if (t == 0) {
        const float inv = 1.0f / 524288.0f;
        float mean = red[0] * inv;
        float var  = red[1] * inv - mean * mean;
        st2[blk * 2]     = mean;
        st2[blk * 2 + 1] = rsqrtf(var + 1e-6f);
    }
}

__global__ void k_norm(const float* __restrict__ st2, const float* __restrict__ gamma,
                       const float* __restrict__ beta, float* __restrict__ out) {
    const int N4 = B * C * H * W / 4;
    int stride = gridDim.x * 256;
    for (int i4 = blockIdx.x * 256 + threadIdx.x; i4 < N4; i4 += stride) {
        int i = i4 * 4;
        int c = (i >> 17) & 127;
        int b = i >> 24;
        int g = c >> 2;
        float mean = st2[(b * 32 + g) * 2];
        float rstd = st2[(b * 32 + g) * 2 + 1];
        float ga = gamma[c], be = beta[c];
        float4 v = *(float4*)(out + i);
        float n0 = (v.x - mean) * rstd * ga + be;
        float n1 = (v.y - mean) * rstd * ga + be;
        float n2 = (v.z - mean) * rstd * ga + be;
        float n3 = (v.w - mean) * rstd * ga + be;
        v.x = n0 / (1.0f + __expf(-n0));
        v.y = n1 / (1.0f + __expf(-n1));
        v.z = n2 / (1.0f + __expf(-n2));
        v.w = n3 / (1.0f + __expf(-n3));
        *(float4*)(out + i) = v;
    }
}

// ---------------------------------------------------------------------------
extern "C" void kernel_launch(void* const* d_in, const int* in_sizes, int n_in,
                              void* d_out, int out_size, void* d_ws, size_t ws_size,
                              hipStream_t stream) {
    const float* x      = (const float*)d_in[0];
    const float* v      = (const float*)d_in[1];
    const float* Wq     = (const float*)d_in[2];
    const float* Wk     = (const float*)d_in[3];
    const float* Wv     = (const float*)d_in[4];
    const float* Wo     = (const float*)d_in[5];
    const float* bo     = (const float*)d_in[6];
    const float* mask_w = (const float*)d_in[7];
    const float* conv_w = (const float*)d_in[8];
    const float* conv_b = (const float*)d_in[9];
    const float* gng    = (const float*)d_in[10];
    const float* gnb    = (const float*)d_in[11];

    float* out  = (float*)d_out;
    float* mout = out + B * C * H * W;
    // d_out's out-region is dead until k_convg writes it -> first 64 MB holds
    // the bf16 attn feature (consumed by k_cat strictly before k_convg).
    ushort* af16 = (ushort*)d_out;

    char*  wsb  = (char*)d_ws;
    ushort* catn  = (ushort*)(wsb + WS_CATN);
    ushort* kq16  = (ushort*)(wsb + WS_KQ);
    ushort* voT16 = (ushort*)(wsb + WS_VOT);
    float*  pb    = (float*)(wsb + WS_PB);
    ushort* w9    = (ushort*)(wsb + WS_W9);
    float*  bin   = (float*)(wsb + WS_BIN);
    float*  st2   = (float*)(wsb + WS_ST2);

    k_binary <<<1,    256, 0, stream>>>(mask_w, bin);
    k_maskout<<<1024, 256, 0, stream>>>(bin, mout);
    k_kv     <<<B * NCOND, 256, 0, stream>>>(v, Wk, Wv, Wq, Wo, kq16, voT16);
    k_w9     <<<1152, 256, 0, stream>>>(conv_w, w9);
    k_attn   <<<4096, 256, 0, stream>>>(x, kq16, voT16, bo, af16);
    k_cat    <<<4096, 256, 0, stream>>>(x, af16, bin, catn);
    k_convg  <<<1024, 512, 0, stream>>>(catn, w9, conv_b, out, pb);
    k_stats2 <<<64,   256, 0, stream>>>(pb, st2);
    k_norm   <<<2048, 256, 0, stream>>>(st2, gng, gnb, out);
}